// Round 1
// baseline (764.077 us; speedup 1.0000x reference)
//
#include <hip/hip_runtime.h>
#include <math.h>

// ---------------------------------------------------------------------------
// GAT x2 + folded (v-proj -> out-proj -> fc) + log_softmax
// Plan:
//   build CSR once (count / scan / scatter) -- graph shared by both layers
//   gemm1: h1 = x @ W1, al1_s/al1_d per node        (wave per node, 64 lanes)
//   agg1 : online-softmax aggregation over CSR      (wave per node, 64 lanes)
//   gemm2: h2 = hout1 @ W2, al2_s/al2_d             (8 nodes / 256-thr block)
//   agg2 : same, F=32                               (wave per node, 32 lanes)
//   fold : M = fc . Wo . Wv  (16x32), b_final       (1 block)
//   final: logits = out2 @ M^T + b ; log_softmax    (thread per node)
// ---------------------------------------------------------------------------

__global__ void count_kernel(const int* __restrict__ ei, int E, int N,
                             int* __restrict__ fill) {
    int e = blockIdx.x * blockDim.x + threadIdx.x;
    if (e >= E + N) return;
    int d = (e < E) ? ei[E + e] : (e - E);
    atomicAdd(&fill[d], 1);
}

__global__ __launch_bounds__(1024) void scan_kernel(int* __restrict__ counts,
                                                    int* __restrict__ row_ptr,
                                                    int N) {
    __shared__ int sums[1024];
    int t = threadIdx.x;
    int chunk = (N + 1023) / 1024;
    int start = t * chunk;
    int end = start + chunk; if (end > N) end = N;
    int s = 0;
    for (int i = start; i < end; ++i) s += counts[i];
    sums[t] = s;
    __syncthreads();
    // Hillis-Steele inclusive scan over 1024 partials
    for (int off = 1; off < 1024; off <<= 1) {
        int v = (t >= off) ? sums[t - off] : 0;
        __syncthreads();
        sums[t] += v;
        __syncthreads();
    }
    int run = (t == 0) ? 0 : sums[t - 1];
    for (int i = start; i < end; ++i) {
        int c = counts[i];
        row_ptr[i] = run;
        run += c;
        counts[i] = 0;          // re-zero for the scatter pass
    }
    if (t == 1023) row_ptr[N] = sums[1023];
}

__global__ void scatter_kernel(const int* __restrict__ ei, int E, int N,
                               const int* __restrict__ row_ptr,
                               int* __restrict__ fill, int* __restrict__ esrc) {
    int e = blockIdx.x * blockDim.x + threadIdx.x;
    if (e >= E + N) return;
    int s, d;
    if (e < E) { s = ei[e]; d = ei[E + e]; } else { s = e - E; d = e - E; }
    int pos = row_ptr[d] + atomicAdd(&fill[d], 1);
    esrc[pos] = s;
}

// h1 = x @ W1   (x: [N,128], W1: [128,64]); also al_s[n,h], al_d[n,h]
__global__ __launch_bounds__(256) void gemm1_kernel(
    const float* __restrict__ x, const float* __restrict__ W,
    const float* __restrict__ a_src, const float* __restrict__ a_dst,
    float* __restrict__ h, float* __restrict__ als, float* __restrict__ ald,
    int N) {
    __shared__ float xs[4][128];
    int wave = threadIdx.x >> 6;
    int lane = threadIdx.x & 63;
    int n = blockIdx.x * 4 + wave;
    if (n < N) {
        const float2* xr = (const float2*)(x + (size_t)n * 128);
        ((float2*)xs[wave])[lane] = xr[lane];
    }
    __syncthreads();
    if (n >= N) return;
    const float* xw = xs[wave];
    float acc = 0.f;
#pragma unroll 4
    for (int k = 0; k < 128; ++k) acc += xw[k] * W[k * 64 + lane];
    h[(size_t)n * 64 + lane] = acc;
    float ps = acc * a_src[lane];   // lane = hd*8 + c, a flat [8,8]
    float pd = acc * a_dst[lane];
    ps += __shfl_xor(ps, 1); ps += __shfl_xor(ps, 2); ps += __shfl_xor(ps, 4);
    pd += __shfl_xor(pd, 1); pd += __shfl_xor(pd, 2); pd += __shfl_xor(pd, 4);
    if ((lane & 7) == 0) {
        int hd = lane >> 3;
        als[n * 8 + hd] = ps;
        ald[n * 8 + hd] = pd;
    }
}

// h2 = hin @ W2  (hin: [N,64], W2: [64,32]); also al2_s/al2_d (heads=8, C=4)
__global__ __launch_bounds__(256) void gemm2_kernel(
    const float* __restrict__ hin, const float* __restrict__ W,
    const float* __restrict__ a_src, const float* __restrict__ a_dst,
    float* __restrict__ h2, float* __restrict__ als, float* __restrict__ ald,
    int N) {
    __shared__ float rows[8 * 64];
    __shared__ float Ws[64 * 32];
    int t = threadIdx.x;
    int nb = blockIdx.x * 8;
    for (int i = t; i < 64 * 32; i += 256) Ws[i] = W[i];
    int nload = N - nb; if (nload > 8) nload = 8;
    for (int i = t; i < nload * 64; i += 256) rows[i] = hin[(size_t)nb * 64 + i];
    __syncthreads();
    int g = t >> 5, l = t & 31;
    int n = nb + g;
    if (n >= N) return;
    float acc = 0.f;
#pragma unroll 8
    for (int k = 0; k < 64; ++k) acc += rows[g * 64 + k] * Ws[k * 32 + l];
    h2[(size_t)n * 32 + l] = acc;
    float ps = acc * a_src[l];      // l = hd*4 + c, a flat [8,4]
    float pd = acc * a_dst[l];
    ps += __shfl_xor(ps, 1); ps += __shfl_xor(ps, 2);
    pd += __shfl_xor(pd, 1); pd += __shfl_xor(pd, 2);
    if ((l & 3) == 0) {
        int hd = l >> 2;
        als[n * 8 + hd] = ps;
        ald[n * 8 + hd] = pd;
    }
}

// Online-softmax edge aggregation: one wave per dst node, lane = hd*C + c.
template <int F, int H, int C>
__global__ __launch_bounds__(256) void agg_kernel(
    const int* __restrict__ row_ptr, const int* __restrict__ esrc,
    const float* __restrict__ feat, const float* __restrict__ als,
    const float* __restrict__ ald_arr, const float* __restrict__ bias,
    float* __restrict__ out, int N) {
    int wave = threadIdx.x >> 6;
    int lane = threadIdx.x & 63;
    int n = blockIdx.x * 4 + wave;
    if (n >= N || lane >= F) return;
    int hd = lane / C;
    float ald = ald_arr[n * H + hd];
    int beg = row_ptr[n], end = row_ptr[n + 1];
    float m = -1e30f, d = 0.f, acc = 0.f;
    for (int i = beg; i < end; ++i) {
        int s = esrc[i];                       // wave-uniform
        float e = als[s * H + hd] + ald;
        e = (e > 0.f) ? e : 0.2f * e;          // leaky_relu(0.2)
        float m2 = fmaxf(m, e);
        float sc = __expf(m - m2);
        float w  = __expf(e - m2);
        float hv = feat[(size_t)s * F + lane];
        d = d * sc + w;
        acc = acc * sc + w * hv;
        m = m2;
    }
    float o = acc / (d + 1e-16f) + bias[lane];
    o = (o > 0.f) ? o : (__expf(o) - 1.0f);    // ELU
    out[(size_t)n * F + lane] = o;
}

// Fold v-proj (in_proj rows 64..95), out_proj, fc into M[16][32], bf[16]
__global__ __launch_bounds__(256) void fold_kernel(
    const float* __restrict__ in_proj_w, const float* __restrict__ in_proj_b,
    const float* __restrict__ out_proj_w, const float* __restrict__ out_proj_b,
    const float* __restrict__ fc_w, const float* __restrict__ fc_b,
    float* __restrict__ M, float* __restrict__ bf) {
    __shared__ float Wvo[32 * 32];
    __shared__ float bvo[32];
    const float* Wv = in_proj_w + 64 * 32;
    const float* bv = in_proj_b + 64;
    int t = threadIdx.x;
    for (int idx = t; idx < 1024; idx += 256) {
        int i = idx >> 5, j = idx & 31;
        float s = 0.f;
        for (int k = 0; k < 32; ++k) s += out_proj_w[i * 32 + k] * Wv[k * 32 + j];
        Wvo[idx] = s;
    }
    if (t < 32) {
        float s = 0.f;
        for (int k = 0; k < 32; ++k) s += out_proj_w[t * 32 + k] * bv[k];
        bvo[t] = s + out_proj_b[t];
    }
    __syncthreads();
    for (int idx = t; idx < 16 * 32; idx += 256) {
        int c = idx >> 5, j = idx & 31;
        float s = 0.f;
        for (int i = 0; i < 32; ++i) s += fc_w[c * 32 + i] * Wvo[i * 32 + j];
        M[idx] = s;
    }
    if (t < 16) {
        float s = 0.f;
        for (int i = 0; i < 32; ++i) s += fc_w[t * 32 + i] * bvo[i];
        bf[t] = s + fc_b[t];
    }
}

__global__ __launch_bounds__(256) void final_kernel(
    const float* __restrict__ h, const float* __restrict__ M,
    const float* __restrict__ bf, float* __restrict__ out, int N) {
    __shared__ float Ms[16 * 32];
    __shared__ float bfs[16];
    int t = threadIdx.x;
    for (int i = t; i < 512; i += 256) Ms[i] = M[i];
    if (t < 16) bfs[t] = bf[t];
    __syncthreads();
    int n = blockIdx.x * 256 + t;
    if (n >= N) return;
    float hv[32];
    const float4* hp = (const float4*)(h + (size_t)n * 32);
#pragma unroll
    for (int i = 0; i < 8; ++i) {
        float4 v = hp[i];
        hv[4 * i] = v.x; hv[4 * i + 1] = v.y; hv[4 * i + 2] = v.z; hv[4 * i + 3] = v.w;
    }
    float lg[16];
    float mx = -1e30f;
#pragma unroll
    for (int c = 0; c < 16; ++c) {
        float s = bfs[c];
#pragma unroll
        for (int j = 0; j < 32; ++j) s += Ms[c * 32 + j] * hv[j];
        lg[c] = s;
        mx = fmaxf(mx, s);
    }
    float se = 0.f;
#pragma unroll
    for (int c = 0; c < 16; ++c) se += __expf(lg[c] - mx);
    float lse = mx + __logf(se);
    float4* op = (float4*)(out + (size_t)n * 16);
#pragma unroll
    for (int i = 0; i < 4; ++i)
        op[i] = make_float4(lg[4 * i] - lse, lg[4 * i + 1] - lse,
                            lg[4 * i + 2] - lse, lg[4 * i + 3] - lse);
}

extern "C" void kernel_launch(void* const* d_in, const int* in_sizes, int n_in,
                              void* d_out, int out_size, void* d_ws, size_t ws_size,
                              hipStream_t stream) {
    const float* x   = (const float*)d_in[0];
    const int*   ei  = (const int*)d_in[1];
    const float* W1  = (const float*)d_in[2];
    const float* a1s = (const float*)d_in[3];
    const float* a1d = (const float*)d_in[4];
    const float* b1  = (const float*)d_in[5];
    const float* W2  = (const float*)d_in[6];
    const float* a2s = (const float*)d_in[7];
    const float* a2d = (const float*)d_in[8];
    const float* b2  = (const float*)d_in[9];
    const float* ipw = (const float*)d_in[10];
    const float* ipb = (const float*)d_in[11];
    const float* opw = (const float*)d_in[12];
    const float* opb = (const float*)d_in[13];
    const float* fcw = (const float*)d_in[14];
    const float* fcb = (const float*)d_in[15];
    float* out = (float*)d_out;

    int N = in_sizes[0] / 128;
    int E = in_sizes[1] / 2;
    int Et = E + N;

    char* ws = (char*)d_ws;
    size_t off = 0;
    auto alloc = [&](size_t bytes) -> void* {
        void* p = ws + off;
        off += bytes;
        off = (off + 255) & ~(size_t)255;
        return p;
    };
    int*   fill   = (int*)alloc((size_t)N * 4);
    int*   rowp   = (int*)alloc((size_t)(N + 1) * 4);
    int*   esrc   = (int*)alloc((size_t)Et * 4);
    float* h1     = (float*)alloc((size_t)N * 64 * 4);
    float* al1s   = (float*)alloc((size_t)N * 8 * 4);
    float* al1d   = (float*)alloc((size_t)N * 8 * 4);
    float* hout1  = (float*)alloc((size_t)N * 64 * 4);
    float* h2     = (float*)alloc((size_t)N * 32 * 4);
    float* al2s   = (float*)alloc((size_t)N * 8 * 4);
    float* al2d   = (float*)alloc((size_t)N * 8 * 4);
    float* out2   = (float*)alloc((size_t)N * 32 * 4);
    float* Mf     = (float*)alloc(512 * 4);
    float* bff    = (float*)alloc(16 * 4);
    (void)ws_size; (void)n_in; (void)out_size;

    const int tb = 256;
    hipMemsetAsync(fill, 0, (size_t)N * 4, stream);
    count_kernel<<<(Et + tb - 1) / tb, tb, 0, stream>>>(ei, E, N, fill);
    scan_kernel<<<1, 1024, 0, stream>>>(fill, rowp, N);
    scatter_kernel<<<(Et + tb - 1) / tb, tb, 0, stream>>>(ei, E, N, rowp, fill, esrc);

    gemm1_kernel<<<(N + 3) / 4, 256, 0, stream>>>(x, W1, a1s, a1d, h1, al1s, al1d, N);
    fold_kernel<<<1, 256, 0, stream>>>(ipw, ipb, opw, opb, fcw, fcb, Mf, bff);
    agg_kernel<64, 8, 8><<<(N + 3) / 4, 256, 0, stream>>>(rowp, esrc, h1, al1s, al1d, b1, hout1, N);
    gemm2_kernel<<<(N + 7) / 8, 256, 0, stream>>>(hout1, W2, a2s, a2d, h2, al2s, al2d, N);
    agg_kernel<32, 8, 4><<<(N + 3) / 4, 256, 0, stream>>>(rowp, esrc, h2, al2s, al2d, b2, out2, N);
    final_kernel<<<(N + 255) / 256, 256, 0, stream>>>(out2, Mf, bff, out, N);
}

// Round 2
// 617.791 us; speedup vs baseline: 1.2368x; 1.2368x over previous
//
#include <hip/hip_runtime.h>
#include <hip/hip_bf16.h>
#include <math.h>

// ---------------------------------------------------------------------------
// GAT x2 + folded (v-proj -> out-proj -> fc) + log_softmax
//   CSR build once (count / scan / scatter) -- graph shared by both layers
//   gemm1: h1(bf16) = x @ W1, al1_s/al1_d       (wave per node)
//   gat_agg<64,8>: 3-phase (max / denom / pure-FMA aggregate), no chain
//   gemm2: h2(bf16) = hout1 @ W2, al2_s/al2_d   (8 nodes / block)
//   gat_agg<32,4>: same, 2 nodes per wave
//   fold:  M = fc . Wo . Wv (16x32) ; final: matvec + log_softmax
// ---------------------------------------------------------------------------

__global__ void count_kernel(const int* __restrict__ ei, int E, int N,
                             int* __restrict__ fill) {
    int e = blockIdx.x * blockDim.x + threadIdx.x;
    if (e >= E + N) return;
    int d = (e < E) ? ei[E + e] : (e - E);
    atomicAdd(&fill[d], 1);
}

__global__ __launch_bounds__(1024) void scan_kernel(int* __restrict__ counts,
                                                    int* __restrict__ row_ptr,
                                                    int N) {
    __shared__ int sums[1024];
    int t = threadIdx.x;
    int chunk = (N + 1023) / 1024;
    int start = t * chunk;
    int end = start + chunk; if (end > N) end = N;
    int s = 0;
    for (int i = start; i < end; ++i) s += counts[i];
    sums[t] = s;
    __syncthreads();
    for (int off = 1; off < 1024; off <<= 1) {
        int v = (t >= off) ? sums[t - off] : 0;
        __syncthreads();
        sums[t] += v;
        __syncthreads();
    }
    int run = (t == 0) ? 0 : sums[t - 1];
    for (int i = start; i < end; ++i) {
        int c = counts[i];
        row_ptr[i] = run;
        run += c;
        counts[i] = 0;          // re-zero for the scatter pass
    }
    if (t == 1023) row_ptr[N] = sums[1023];
}

__global__ void scatter_kernel(const int* __restrict__ ei, int E, int N,
                               const int* __restrict__ row_ptr,
                               int* __restrict__ fill, int* __restrict__ esrc) {
    int e = blockIdx.x * blockDim.x + threadIdx.x;
    if (e >= E + N) return;
    int s, d;
    if (e < E) { s = ei[e]; d = ei[E + e]; } else { s = e - E; d = e - E; }
    int pos = row_ptr[d] + atomicAdd(&fill[d], 1);
    esrc[pos] = s;
}

// h1(bf16) = x @ W1  (x: [N,128], W1: [128,64]); als/ald: [N,8]
__global__ __launch_bounds__(256) void gemm1_kernel(
    const float* __restrict__ x, const float* __restrict__ W,
    const float* __restrict__ a_src, const float* __restrict__ a_dst,
    __hip_bfloat16* __restrict__ h, float* __restrict__ als,
    float* __restrict__ ald, int N) {
    __shared__ float xs[4][128];
    int wave = threadIdx.x >> 6;
    int lane = threadIdx.x & 63;
    int n = blockIdx.x * 4 + wave;
    if (n < N) {
        const float2* xr = (const float2*)(x + (size_t)n * 128);
        ((float2*)xs[wave])[lane] = xr[lane];
    }
    __syncthreads();
    if (n >= N) return;
    const float* xw = xs[wave];
    float acc = 0.f;
#pragma unroll 4
    for (int k = 0; k < 128; ++k) acc += xw[k] * W[k * 64 + lane];
    h[(size_t)n * 64 + lane] = __float2bfloat16(acc);
    float ps = acc * a_src[lane];   // lane = hd*8 + c, a flat [8,8]
    float pd = acc * a_dst[lane];
    ps += __shfl_xor(ps, 1); ps += __shfl_xor(ps, 2); ps += __shfl_xor(ps, 4);
    pd += __shfl_xor(pd, 1); pd += __shfl_xor(pd, 2); pd += __shfl_xor(pd, 4);
    if ((lane & 7) == 0) {
        int hd = lane >> 3;
        als[n * 8 + hd] = ps;
        ald[n * 8 + hd] = pd;
    }
}

// h2(bf16) = hin @ W2  (hin: [N,64] f32, W2: [64,32]); al2: heads=8, C=4
__global__ __launch_bounds__(256) void gemm2_kernel(
    const float* __restrict__ hin, const float* __restrict__ W,
    const float* __restrict__ a_src, const float* __restrict__ a_dst,
    __hip_bfloat16* __restrict__ h2, float* __restrict__ als,
    float* __restrict__ ald, int N) {
    __shared__ float rows[8 * 64];
    __shared__ float Ws[64 * 32];
    int t = threadIdx.x;
    int nb = blockIdx.x * 8;
    for (int i = t; i < 64 * 32; i += 256) Ws[i] = W[i];
    int nload = N - nb; if (nload > 8) nload = 8;
    for (int i = t; i < nload * 64; i += 256) rows[i] = hin[(size_t)nb * 64 + i];
    __syncthreads();
    int g = t >> 5, l = t & 31;
    int n = nb + g;
    if (n >= N) return;
    float acc = 0.f;
#pragma unroll 8
    for (int k = 0; k < 64; ++k) acc += rows[g * 64 + k] * Ws[k * 32 + l];
    h2[(size_t)n * 32 + l] = __float2bfloat16(acc);
    float ps = acc * a_src[l];      // l = hd*4 + c, a flat [8,4]
    float pd = acc * a_dst[l];
    ps += __shfl_xor(ps, 1); ps += __shfl_xor(ps, 2);
    pd += __shfl_xor(pd, 1); pd += __shfl_xor(pd, 2);
    if ((l & 3) == 0) {
        int hd = l >> 2;
        als[n * 8 + hd] = ps;
        ald[n * 8 + hd] = pd;
    }
}

// Fused 3-phase GAT aggregation. F lanes per node (64/F nodes per wave).
// Phase 1: per-head max over edges (lanes = 8 heads x F/8 edge slots).
// Phase 2: per-head denom = sum exp(e - m).
// Phase 3: pure-FMA aggregate, unroll x4, no loop-carried dependency.
template <int F, int C>
__global__ __launch_bounds__(256) void gat_agg_kernel(
    const int* __restrict__ rowp, const int* __restrict__ esrc,
    const __hip_bfloat16* __restrict__ feat, const float* __restrict__ als,
    const float* __restrict__ ald_arr, const float* __restrict__ bias,
    float* __restrict__ out, int N) {
    const int lane = threadIdx.x & 63;
    const int waveid = threadIdx.x >> 6;
    const int sub = lane / F;
    const int sl = lane % F;
    const int subbase = sub * F;
    int n = (blockIdx.x * 4 + waveid) * (64 / F) + sub;
    if (n >= N) return;
    int beg = rowp[n], end = rowp[n + 1];

    // phase 1+2 layout: eoff = sl>>3 (F/8 edge slots), hd = sl&7
    int eoff = sl >> 3, hd = sl & 7;
    float aldv = ald_arr[n * 8 + hd];
    float m = -1e30f;
    for (int i = beg + eoff; i < end; i += F / 8) {
        float e = als[esrc[i] * 8 + hd] + aldv;
        m = fmaxf(m, (e > 0.f) ? e : 0.2f * e);
    }
    m = fmaxf(m, __shfl_xor(m, 8));
    m = fmaxf(m, __shfl_xor(m, 16));
    if (F == 64) m = fmaxf(m, __shfl_xor(m, 32));
    float d = 0.f;
    for (int i = beg + eoff; i < end; i += F / 8) {
        float e = als[esrc[i] * 8 + hd] + aldv;
        e = (e > 0.f) ? e : 0.2f * e;
        d += __expf(e - m);
    }
    d += __shfl_xor(d, 8);
    d += __shfl_xor(d, 16);
    if (F == 64) d += __shfl_xor(d, 32);

    // phase 3 layout: lane sl covers channel, head hd3 = sl / C
    int hd3 = sl / C;
    float m3 = __shfl(m, subbase + hd3);
    float dinv = 1.0f / (__shfl(d, subbase + hd3) + 1e-16f);
    float ald3 = __shfl(aldv, subbase + hd3);
    float acc0 = 0.f, acc1 = 0.f, acc2 = 0.f, acc3 = 0.f;
    int i = beg;
    for (; i + 4 <= end; i += 4) {
        int s0 = esrc[i], s1 = esrc[i + 1], s2 = esrc[i + 2], s3 = esrc[i + 3];
        float e0 = als[s0 * 8 + hd3] + ald3;
        float e1 = als[s1 * 8 + hd3] + ald3;
        float e2 = als[s2 * 8 + hd3] + ald3;
        float e3 = als[s3 * 8 + hd3] + ald3;
        e0 = (e0 > 0.f) ? e0 : 0.2f * e0;
        e1 = (e1 > 0.f) ? e1 : 0.2f * e1;
        e2 = (e2 > 0.f) ? e2 : 0.2f * e2;
        e3 = (e3 > 0.f) ? e3 : 0.2f * e3;
        float w0 = __expf(e0 - m3), w1 = __expf(e1 - m3);
        float w2 = __expf(e2 - m3), w3 = __expf(e3 - m3);
        float f0 = __bfloat162float(feat[(size_t)s0 * F + sl]);
        float f1 = __bfloat162float(feat[(size_t)s1 * F + sl]);
        float f2 = __bfloat162float(feat[(size_t)s2 * F + sl]);
        float f3 = __bfloat162float(feat[(size_t)s3 * F + sl]);
        acc0 += w0 * f0; acc1 += w1 * f1; acc2 += w2 * f2; acc3 += w3 * f3;
    }
    for (; i < end; ++i) {
        int s = esrc[i];
        float e = als[s * 8 + hd3] + ald3;
        e = (e > 0.f) ? e : 0.2f * e;
        acc0 += __expf(e - m3) * __bfloat162float(feat[(size_t)s * F + sl]);
    }
    float o = (acc0 + acc1 + acc2 + acc3) * dinv + bias[sl];
    o = (o > 0.f) ? o : (__expf(o) - 1.0f);   // ELU
    out[(size_t)n * F + sl] = o;
}

// Fold v-proj (in_proj rows 64..95), out_proj, fc into M[16][32], bf[16]
__global__ __launch_bounds__(256) void fold_kernel(
    const float* __restrict__ in_proj_w, const float* __restrict__ in_proj_b,
    const float* __restrict__ out_proj_w, const float* __restrict__ out_proj_b,
    const float* __restrict__ fc_w, const float* __restrict__ fc_b,
    float* __restrict__ M, float* __restrict__ bf) {
    __shared__ float Wvo[32 * 32];
    __shared__ float bvo[32];
    const float* Wv = in_proj_w + 64 * 32;
    const float* bv = in_proj_b + 64;
    int t = threadIdx.x;
    for (int idx = t; idx < 1024; idx += 256) {
        int i = idx >> 5, j = idx & 31;
        float s = 0.f;
        for (int k = 0; k < 32; ++k) s += out_proj_w[i * 32 + k] * Wv[k * 32 + j];
        Wvo[idx] = s;
    }
    if (t < 32) {
        float s = 0.f;
        for (int k = 0; k < 32; ++k) s += out_proj_w[t * 32 + k] * bv[k];
        bvo[t] = s + out_proj_b[t];
    }
    __syncthreads();
    for (int idx = t; idx < 16 * 32; idx += 256) {
        int c = idx >> 5, j = idx & 31;
        float s = 0.f;
        for (int i = 0; i < 32; ++i) s += fc_w[c * 32 + i] * Wvo[i * 32 + j];
        M[idx] = s;
    }
    if (t < 16) {
        float s = 0.f;
        for (int i = 0; i < 32; ++i) s += fc_w[t * 32 + i] * bvo[i];
        bf[t] = s + fc_b[t];
    }
}

__global__ __launch_bounds__(256) void final_kernel(
    const float* __restrict__ h, const float* __restrict__ M,
    const float* __restrict__ bf, float* __restrict__ out, int N) {
    __shared__ float Ms[16 * 32];
    __shared__ float bfs[16];
    int t = threadIdx.x;
    for (int i = t; i < 512; i += 256) Ms[i] = M[i];
    if (t < 16) bfs[t] = bf[t];
    __syncthreads();
    int n = blockIdx.x * 256 + t;
    if (n >= N) return;
    float hv[32];
    const float4* hp = (const float4*)(h + (size_t)n * 32);
#pragma unroll
    for (int i = 0; i < 8; ++i) {
        float4 v = hp[i];
        hv[4 * i] = v.x; hv[4 * i + 1] = v.y; hv[4 * i + 2] = v.z; hv[4 * i + 3] = v.w;
    }
    float lg[16];
    float mx = -1e30f;
#pragma unroll
    for (int c = 0; c < 16; ++c) {
        float s = bfs[c];
#pragma unroll
        for (int j = 0; j < 32; ++j) s += Ms[c * 32 + j] * hv[j];
        lg[c] = s;
        mx = fmaxf(mx, s);
    }
    float se = 0.f;
#pragma unroll
    for (int c = 0; c < 16; ++c) se += __expf(lg[c] - mx);
    float lse = mx + __logf(se);
    float4* op = (float4*)(out + (size_t)n * 16);
#pragma unroll
    for (int i = 0; i < 4; ++i)
        op[i] = make_float4(lg[4 * i] - lse, lg[4 * i + 1] - lse,
                            lg[4 * i + 2] - lse, lg[4 * i + 3] - lse);
}

extern "C" void kernel_launch(void* const* d_in, const int* in_sizes, int n_in,
                              void* d_out, int out_size, void* d_ws, size_t ws_size,
                              hipStream_t stream) {
    const float* x   = (const float*)d_in[0];
    const int*   ei  = (const int*)d_in[1];
    const float* W1  = (const float*)d_in[2];
    const float* a1s = (const float*)d_in[3];
    const float* a1d = (const float*)d_in[4];
    const float* b1  = (const float*)d_in[5];
    const float* W2  = (const float*)d_in[6];
    const float* a2s = (const float*)d_in[7];
    const float* a2d = (const float*)d_in[8];
    const float* b2  = (const float*)d_in[9];
    const float* ipw = (const float*)d_in[10];
    const float* ipb = (const float*)d_in[11];
    const float* opw = (const float*)d_in[12];
    const float* opb = (const float*)d_in[13];
    const float* fcw = (const float*)d_in[14];
    const float* fcb = (const float*)d_in[15];
    float* out = (float*)d_out;

    int N = in_sizes[0] / 128;
    int E = in_sizes[1] / 2;
    int Et = E + N;

    char* ws = (char*)d_ws;
    size_t off = 0;
    auto alloc = [&](size_t bytes) -> void* {
        void* p = ws + off;
        off += bytes;
        off = (off + 255) & ~(size_t)255;
        return p;
    };
    int*   fill  = (int*)alloc((size_t)N * 4);
    int*   rowp  = (int*)alloc((size_t)(N + 1) * 4);
    int*   esrc  = (int*)alloc((size_t)Et * 4);
    __hip_bfloat16* h1 = (__hip_bfloat16*)alloc((size_t)N * 64 * 2);
    float* al1s  = (float*)alloc((size_t)N * 8 * 4);
    float* al1d  = (float*)alloc((size_t)N * 8 * 4);
    float* hout1 = (float*)alloc((size_t)N * 64 * 4);
    __hip_bfloat16* h2 = (__hip_bfloat16*)alloc((size_t)N * 32 * 2);
    float* al2s  = (float*)alloc((size_t)N * 8 * 4);
    float* al2d  = (float*)alloc((size_t)N * 8 * 4);
    float* out2  = (float*)alloc((size_t)N * 32 * 4);
    float* Mf    = (float*)alloc(512 * 4);
    float* bff   = (float*)alloc(16 * 4);
    (void)ws_size; (void)n_in; (void)out_size;

    const int tb = 256;
    hipMemsetAsync(fill, 0, (size_t)N * 4, stream);
    count_kernel<<<(Et + tb - 1) / tb, tb, 0, stream>>>(ei, E, N, fill);
    scan_kernel<<<1, 1024, 0, stream>>>(fill, rowp, N);
    scatter_kernel<<<(Et + tb - 1) / tb, tb, 0, stream>>>(ei, E, N, rowp, fill, esrc);

    gemm1_kernel<<<(N + 3) / 4, 256, 0, stream>>>(x, W1, a1s, a1d, h1, al1s, al1d, N);
    fold_kernel<<<1, 256, 0, stream>>>(ipw, ipb, opw, opb, fcw, fcb, Mf, bff);
    gat_agg_kernel<64, 8><<<(N + 3) / 4, 256, 0, stream>>>(
        rowp, esrc, h1, al1s, al1d, b1, hout1, N);
    gemm2_kernel<<<(N + 7) / 8, 256, 0, stream>>>(hout1, W2, a2s, a2d, h2, al2s, al2d, N);
    gat_agg_kernel<32, 4><<<(N + 7) / 8, 256, 0, stream>>>(
        rowp, esrc, h2, al2s, al2d, b2, out2, N);
    final_kernel<<<(N + 255) / 256, 256, 0, stream>>>(out2, Mf, bff, out, N);
}

// Round 3
// 534.426 us; speedup vs baseline: 1.4297x; 1.1560x over previous
//
#include <hip/hip_runtime.h>
#include <hip/hip_bf16.h>
#include <math.h>

// ---------------------------------------------------------------------------
// GAT x2 + folded (v-proj -> out-proj -> fc) + log_softmax
//   CSR build once per call (count / 3-level scan / scatter)
//   gemm1: h1(bf16) = x @ W1, al1_s/al1_d       (wave per node)
//   gat_agg<64,8>: 3-phase (max / denom / pure-FMA aggregate), no chain
//   gemm2: h2(bf16) = hout1 @ W2, al2_s/al2_d   (8 nodes / block)
//   gat_agg<32,4>: same, 2 nodes per wave
//   fold:  M = fc . Wo . Wv (16x32) ; final: matvec + log_softmax
// ---------------------------------------------------------------------------

__global__ void count_kernel(const int* __restrict__ ei, int E, int N,
                             int* __restrict__ fill) {
    int e = blockIdx.x * blockDim.x + threadIdx.x;
    if (e >= E + N) return;
    int d = (e < E) ? ei[E + e] : (e - E);
    atomicAdd(&fill[d], 1);
}

// 3-level exclusive scan over counts[N] -> rowp[N+1]
// scan1: per-block (256) local exclusive scan + block sums
__global__ __launch_bounds__(256) void scan1_kernel(
    const int* __restrict__ counts, int* __restrict__ rowp,
    int* __restrict__ bsum, int N) {
    __shared__ int s[256];
    int t = threadIdx.x;
    int i = blockIdx.x * 256 + t;
    int v = (i < N) ? counts[i] : 0;
    s[t] = v;
    __syncthreads();
    for (int off = 1; off < 256; off <<= 1) {
        int u = (t >= off) ? s[t - off] : 0;
        __syncthreads();
        s[t] += u;
        __syncthreads();
    }
    if (i < N) rowp[i] = s[t] - v;          // exclusive
    if (t == 255) bsum[blockIdx.x] = s[255];
}

// scan2: single block scans block sums (B <= 256; N <= 65536)
__global__ __launch_bounds__(256) void scan2_kernel(
    int* __restrict__ bsum, int* __restrict__ boff,
    int* __restrict__ rowp, int B, int N) {
    __shared__ int s[256];
    int t = threadIdx.x;
    int v = (t < B) ? bsum[t] : 0;
    s[t] = v;
    __syncthreads();
    for (int off = 1; off < 256; off <<= 1) {
        int u = (t >= off) ? s[t - off] : 0;
        __syncthreads();
        s[t] += u;
        __syncthreads();
    }
    if (t < B) boff[t] = s[t] - v;          // exclusive block offsets
    if (t == 255) rowp[N] = s[255];         // grand total
}

// scan3: add block offsets; re-zero fill for the scatter cursor
__global__ __launch_bounds__(256) void scan3_kernel(
    int* __restrict__ rowp, const int* __restrict__ boff,
    int* __restrict__ fill, int N) {
    int i = blockIdx.x * 256 + threadIdx.x;
    if (i < N) {
        rowp[i] += boff[i >> 8];
        fill[i] = 0;
    }
}

__global__ void scatter_kernel(const int* __restrict__ ei, int E, int N,
                               const int* __restrict__ row_ptr,
                               int* __restrict__ fill, int* __restrict__ esrc) {
    int e = blockIdx.x * blockDim.x + threadIdx.x;
    if (e >= E + N) return;
    int s, d;
    if (e < E) { s = ei[e]; d = ei[E + e]; } else { s = e - E; d = e - E; }
    int pos = row_ptr[d] + atomicAdd(&fill[d], 1);
    esrc[pos] = s;
}

// h1(bf16) = x @ W1  (x: [N,128], W1: [128,64]); als/ald: [N,8]
__global__ __launch_bounds__(256) void gemm1_kernel(
    const float* __restrict__ x, const float* __restrict__ W,
    const float* __restrict__ a_src, const float* __restrict__ a_dst,
    __hip_bfloat16* __restrict__ h, float* __restrict__ als,
    float* __restrict__ ald, int N) {
    __shared__ float xs[4][128];
    int wave = threadIdx.x >> 6;
    int lane = threadIdx.x & 63;
    int n = blockIdx.x * 4 + wave;
    if (n < N) {
        const float2* xr = (const float2*)(x + (size_t)n * 128);
        ((float2*)xs[wave])[lane] = xr[lane];
    }
    __syncthreads();
    if (n >= N) return;
    const float* xw = xs[wave];
    float acc = 0.f;
#pragma unroll 4
    for (int k = 0; k < 128; ++k) acc += xw[k] * W[k * 64 + lane];
    h[(size_t)n * 64 + lane] = __float2bfloat16(acc);
    float ps = acc * a_src[lane];   // lane = hd*8 + c, a flat [8,8]
    float pd = acc * a_dst[lane];
    ps += __shfl_xor(ps, 1); ps += __shfl_xor(ps, 2); ps += __shfl_xor(ps, 4);
    pd += __shfl_xor(pd, 1); pd += __shfl_xor(pd, 2); pd += __shfl_xor(pd, 4);
    if ((lane & 7) == 0) {
        int hd = lane >> 3;
        als[n * 8 + hd] = ps;
        ald[n * 8 + hd] = pd;
    }
}

// h2(bf16) = hin @ W2  (hin: [N,64] f32, W2: [64,32]); al2: heads=8, C=4
__global__ __launch_bounds__(256) void gemm2_kernel(
    const float* __restrict__ hin, const float* __restrict__ W,
    const float* __restrict__ a_src, const float* __restrict__ a_dst,
    __hip_bfloat16* __restrict__ h2, float* __restrict__ als,
    float* __restrict__ ald, int N) {
    __shared__ float rows[8 * 64];
    __shared__ float Ws[64 * 32];
    int t = threadIdx.x;
    int nb = blockIdx.x * 8;
    for (int i = t; i < 64 * 32; i += 256) Ws[i] = W[i];
    int nload = N - nb; if (nload > 8) nload = 8;
    for (int i = t; i < nload * 64; i += 256) rows[i] = hin[(size_t)nb * 64 + i];
    __syncthreads();
    int g = t >> 5, l = t & 31;
    int n = nb + g;
    if (n >= N) return;
    float acc = 0.f;
#pragma unroll 8
    for (int k = 0; k < 64; ++k) acc += rows[g * 64 + k] * Ws[k * 32 + l];
    h2[(size_t)n * 32 + l] = __float2bfloat16(acc);
    float ps = acc * a_src[l];      // l = hd*4 + c, a flat [8,4]
    float pd = acc * a_dst[l];
    ps += __shfl_xor(ps, 1); ps += __shfl_xor(ps, 2);
    pd += __shfl_xor(pd, 1); pd += __shfl_xor(pd, 2);
    if ((l & 3) == 0) {
        int hd = l >> 2;
        als[n * 8 + hd] = ps;
        ald[n * 8 + hd] = pd;
    }
}

// Fused 3-phase GAT aggregation. F lanes per node (64/F nodes per wave).
template <int F, int C>
__global__ __launch_bounds__(256) void gat_agg_kernel(
    const int* __restrict__ rowp, const int* __restrict__ esrc,
    const __hip_bfloat16* __restrict__ feat, const float* __restrict__ als,
    const float* __restrict__ ald_arr, const float* __restrict__ bias,
    float* __restrict__ out, int N) {
    const int lane = threadIdx.x & 63;
    const int waveid = threadIdx.x >> 6;
    const int sub = lane / F;
    const int sl = lane % F;
    const int subbase = sub * F;
    int n = (blockIdx.x * 4 + waveid) * (64 / F) + sub;
    if (n >= N) return;
    int beg = rowp[n], end = rowp[n + 1];

    // phase 1+2 layout: eoff = sl>>3 (F/8 edge slots), hd = sl&7
    int eoff = sl >> 3, hd = sl & 7;
    float aldv = ald_arr[n * 8 + hd];
    float m = -1e30f;
    for (int i = beg + eoff; i < end; i += F / 8) {
        float e = als[esrc[i] * 8 + hd] + aldv;
        m = fmaxf(m, (e > 0.f) ? e : 0.2f * e);
    }
    m = fmaxf(m, __shfl_xor(m, 8));
    m = fmaxf(m, __shfl_xor(m, 16));
    if (F == 64) m = fmaxf(m, __shfl_xor(m, 32));
    float d = 0.f;
    for (int i = beg + eoff; i < end; i += F / 8) {
        float e = als[esrc[i] * 8 + hd] + aldv;
        e = (e > 0.f) ? e : 0.2f * e;
        d += __expf(e - m);
    }
    d += __shfl_xor(d, 8);
    d += __shfl_xor(d, 16);
    if (F == 64) d += __shfl_xor(d, 32);

    // phase 3 layout: lane sl covers channel, head hd3 = sl / C
    int hd3 = sl / C;
    float m3 = __shfl(m, subbase + hd3);
    float dinv = 1.0f / (__shfl(d, subbase + hd3) + 1e-16f);
    float ald3 = __shfl(aldv, subbase + hd3);
    float acc0 = 0.f, acc1 = 0.f, acc2 = 0.f, acc3 = 0.f;
    int i = beg;
    for (; i + 4 <= end; i += 4) {
        int s0 = esrc[i], s1 = esrc[i + 1], s2 = esrc[i + 2], s3 = esrc[i + 3];
        float e0 = als[s0 * 8 + hd3] + ald3;
        float e1 = als[s1 * 8 + hd3] + ald3;
        float e2 = als[s2 * 8 + hd3] + ald3;
        float e3 = als[s3 * 8 + hd3] + ald3;
        e0 = (e0 > 0.f) ? e0 : 0.2f * e0;
        e1 = (e1 > 0.f) ? e1 : 0.2f * e1;
        e2 = (e2 > 0.f) ? e2 : 0.2f * e2;
        e3 = (e3 > 0.f) ? e3 : 0.2f * e3;
        float w0 = __expf(e0 - m3), w1 = __expf(e1 - m3);
        float w2 = __expf(e2 - m3), w3 = __expf(e3 - m3);
        float f0 = __bfloat162float(feat[(size_t)s0 * F + sl]);
        float f1 = __bfloat162float(feat[(size_t)s1 * F + sl]);
        float f2 = __bfloat162float(feat[(size_t)s2 * F + sl]);
        float f3 = __bfloat162float(feat[(size_t)s3 * F + sl]);
        acc0 += w0 * f0; acc1 += w1 * f1; acc2 += w2 * f2; acc3 += w3 * f3;
    }
    for (; i < end; ++i) {
        int s = esrc[i];
        float e = als[s * 8 + hd3] + ald3;
        e = (e > 0.f) ? e : 0.2f * e;
        acc0 += __expf(e - m3) * __bfloat162float(feat[(size_t)s * F + sl]);
    }
    float o = (acc0 + acc1 + acc2 + acc3) * dinv + bias[sl];
    o = (o > 0.f) ? o : (__expf(o) - 1.0f);   // ELU
    out[(size_t)n * F + sl] = o;
}

// Fold v-proj (in_proj rows 64..95), out_proj, fc into M[16][32], bf[16]
__global__ __launch_bounds__(256) void fold_kernel(
    const float* __restrict__ in_proj_w, const float* __restrict__ in_proj_b,
    const float* __restrict__ out_proj_w, const float* __restrict__ out_proj_b,
    const float* __restrict__ fc_w, const float* __restrict__ fc_b,
    float* __restrict__ M, float* __restrict__ bf) {
    __shared__ float Wvo[32 * 32];
    __shared__ float bvo[32];
    const float* Wv = in_proj_w + 64 * 32;
    const float* bv = in_proj_b + 64;
    int t = threadIdx.x;
    for (int idx = t; idx < 1024; idx += 256) {
        int i = idx >> 5, j = idx & 31;
        float s = 0.f;
        for (int k = 0; k < 32; ++k) s += out_proj_w[i * 32 + k] * Wv[k * 32 + j];
        Wvo[idx] = s;
    }
    if (t < 32) {
        float s = 0.f;
        for (int k = 0; k < 32; ++k) s += out_proj_w[t * 32 + k] * bv[k];
        bvo[t] = s + out_proj_b[t];
    }
    __syncthreads();
    for (int idx = t; idx < 16 * 32; idx += 256) {
        int c = idx >> 5, j = idx & 31;
        float s = 0.f;
        for (int i = 0; i < 32; ++i) s += fc_w[c * 32 + i] * Wvo[i * 32 + j];
        M[idx] = s;
    }
    if (t < 16) {
        float s = 0.f;
        for (int i = 0; i < 32; ++i) s += fc_w[t * 32 + i] * bvo[i];
        bf[t] = s + fc_b[t];
    }
}

__global__ __launch_bounds__(256) void final_kernel(
    const float* __restrict__ h, const float* __restrict__ M,
    const float* __restrict__ bf, float* __restrict__ out, int N) {
    __shared__ float Ms[16 * 32];
    __shared__ float bfs[16];
    int t = threadIdx.x;
    for (int i = t; i < 512; i += 256) Ms[i] = M[i];
    if (t < 16) bfs[t] = bf[t];
    __syncthreads();
    int n = blockIdx.x * 256 + t;
    if (n >= N) return;
    float hv[32];
    const float4* hp = (const float4*)(h + (size_t)n * 32);
#pragma unroll
    for (int i = 0; i < 8; ++i) {
        float4 v = hp[i];
        hv[4 * i] = v.x; hv[4 * i + 1] = v.y; hv[4 * i + 2] = v.z; hv[4 * i + 3] = v.w;
    }
    float lg[16];
    float mx = -1e30f;
#pragma unroll
    for (int c = 0; c < 16; ++c) {
        float s = bfs[c];
#pragma unroll
        for (int j = 0; j < 32; ++j) s += Ms[c * 32 + j] * hv[j];
        lg[c] = s;
        mx = fmaxf(mx, s);
    }
    float se = 0.f;
#pragma unroll
    for (int c = 0; c < 16; ++c) se += __expf(lg[c] - mx);
    float lse = mx + __logf(se);
    float4* op = (float4*)(out + (size_t)n * 16);
#pragma unroll
    for (int i = 0; i < 4; ++i)
        op[i] = make_float4(lg[4 * i] - lse, lg[4 * i + 1] - lse,
                            lg[4 * i + 2] - lse, lg[4 * i + 3] - lse);
}

extern "C" void kernel_launch(void* const* d_in, const int* in_sizes, int n_in,
                              void* d_out, int out_size, void* d_ws, size_t ws_size,
                              hipStream_t stream) {
    const float* x   = (const float*)d_in[0];
    const int*   ei  = (const int*)d_in[1];
    const float* W1  = (const float*)d_in[2];
    const float* a1s = (const float*)d_in[3];
    const float* a1d = (const float*)d_in[4];
    const float* b1  = (const float*)d_in[5];
    const float* W2  = (const float*)d_in[6];
    const float* a2s = (const float*)d_in[7];
    const float* a2d = (const float*)d_in[8];
    const float* b2  = (const float*)d_in[9];
    const float* ipw = (const float*)d_in[10];
    const float* ipb = (const float*)d_in[11];
    const float* opw = (const float*)d_in[12];
    const float* opb = (const float*)d_in[13];
    const float* fcw = (const float*)d_in[14];
    const float* fcb = (const float*)d_in[15];
    float* out = (float*)d_out;

    int N = in_sizes[0] / 128;
    int E = in_sizes[1] / 2;
    int Et = E + N;
    int B = (N + 255) / 256;   // scan blocks (<=256 for N<=65536)

    char* ws = (char*)d_ws;
    size_t off = 0;
    auto alloc = [&](size_t bytes) -> void* {
        void* p = ws + off;
        off += bytes;
        off = (off + 255) & ~(size_t)255;
        return p;
    };
    int*   fill  = (int*)alloc((size_t)N * 4);
    int*   rowp  = (int*)alloc((size_t)(N + 1) * 4);
    int*   esrc  = (int*)alloc((size_t)Et * 4);
    int*   bsum  = (int*)alloc(256 * 4);
    int*   boff  = (int*)alloc(256 * 4);
    __hip_bfloat16* h1 = (__hip_bfloat16*)alloc((size_t)N * 64 * 2);
    float* al1s  = (float*)alloc((size_t)N * 8 * 4);
    float* al1d  = (float*)alloc((size_t)N * 8 * 4);
    float* hout1 = (float*)alloc((size_t)N * 64 * 4);
    __hip_bfloat16* h2 = (__hip_bfloat16*)alloc((size_t)N * 32 * 2);
    float* al2s  = (float*)alloc((size_t)N * 8 * 4);
    float* al2d  = (float*)alloc((size_t)N * 8 * 4);
    float* out2  = (float*)alloc((size_t)N * 32 * 4);
    float* Mf    = (float*)alloc(512 * 4);
    float* bff   = (float*)alloc(16 * 4);
    (void)ws_size; (void)n_in; (void)out_size;

    const int tb = 256;
    hipMemsetAsync(fill, 0, (size_t)N * 4, stream);
    count_kernel<<<(Et + tb - 1) / tb, tb, 0, stream>>>(ei, E, N, fill);
    scan1_kernel<<<B, 256, 0, stream>>>(fill, rowp, bsum, N);
    scan2_kernel<<<1, 256, 0, stream>>>(bsum, boff, rowp, B, N);
    scan3_kernel<<<B, 256, 0, stream>>>(rowp, boff, fill, N);
    scatter_kernel<<<(Et + tb - 1) / tb, tb, 0, stream>>>(ei, E, N, rowp, fill, esrc);

    gemm1_kernel<<<(N + 3) / 4, 256, 0, stream>>>(x, W1, a1s, a1d, h1, al1s, al1d, N);
    fold_kernel<<<1, 256, 0, stream>>>(ipw, ipb, opw, opb, fcw, fcb, Mf, bff);
    gat_agg_kernel<64, 8><<<(N + 3) / 4, 256, 0, stream>>>(
        rowp, esrc, h1, al1s, al1d, b1, hout1, N);
    gemm2_kernel<<<(N + 7) / 8, 256, 0, stream>>>(hout1, W2, a2s, a2d, h2, al2s, al2d, N);
    gat_agg_kernel<32, 4><<<(N + 7) / 8, 256, 0, stream>>>(
        rowp, esrc, h2, al2s, al2d, b2, out2, N);
    final_kernel<<<(N + 255) / 256, 256, 0, stream>>>(out2, Mf, bff, out, N);
}

// Round 4
// 468.330 us; speedup vs baseline: 1.6315x; 1.1411x over previous
//
#include <hip/hip_runtime.h>
#include <hip/hip_bf16.h>
#include <math.h>

// ---------------------------------------------------------------------------
// GAT x2 + folded (v-proj -> out-proj -> fc) + log_softmax
//   CSR build once per call (count / 3-level scan / scatter)
//   gemm1: h1(bf16) = x @ W1, al1_s/al1_d       (wave per node)
//   gat_agg64: FUSED single-pass softmax-aggregate (no max: |e|<~3, exp(e)
//              safe in fp32; alpha = exp(e)/sum exp(e) is max-invariant).
//              Wave-uniform edge walk -> readfirstlane-scalarized addresses.
//   gemm2: h2(bf16) = hout1 @ W2, al2_s/al2_d   (8 nodes / block)
//   gat_agg32: same fused pass, 2 nodes per wave (per-lane addressing)
//   fold:  M = fc . Wo . Wv (16x32) ; final: matvec + log_softmax
// ---------------------------------------------------------------------------

__global__ void count_kernel(const int* __restrict__ ei, int E, int N,
                             int* __restrict__ fill) {
    int e = blockIdx.x * blockDim.x + threadIdx.x;
    if (e >= E + N) return;
    int d = (e < E) ? ei[E + e] : (e - E);
    atomicAdd(&fill[d], 1);
}

// 3-level exclusive scan over counts[N] -> rowp[N+1]
__global__ __launch_bounds__(256) void scan1_kernel(
    const int* __restrict__ counts, int* __restrict__ rowp,
    int* __restrict__ bsum, int N) {
    __shared__ int s[256];
    int t = threadIdx.x;
    int i = blockIdx.x * 256 + t;
    int v = (i < N) ? counts[i] : 0;
    s[t] = v;
    __syncthreads();
    for (int off = 1; off < 256; off <<= 1) {
        int u = (t >= off) ? s[t - off] : 0;
        __syncthreads();
        s[t] += u;
        __syncthreads();
    }
    if (i < N) rowp[i] = s[t] - v;          // exclusive
    if (t == 255) bsum[blockIdx.x] = s[255];
}

__global__ __launch_bounds__(256) void scan2_kernel(
    int* __restrict__ bsum, int* __restrict__ boff,
    int* __restrict__ rowp, int B, int N) {
    __shared__ int s[256];
    int t = threadIdx.x;
    int v = (t < B) ? bsum[t] : 0;
    s[t] = v;
    __syncthreads();
    for (int off = 1; off < 256; off <<= 1) {
        int u = (t >= off) ? s[t - off] : 0;
        __syncthreads();
        s[t] += u;
        __syncthreads();
    }
    if (t < B) boff[t] = s[t] - v;          // exclusive block offsets
    if (t == 255) rowp[N] = s[255];         // grand total
}

__global__ __launch_bounds__(256) void scan3_kernel(
    int* __restrict__ rowp, const int* __restrict__ boff,
    int* __restrict__ fill, int N) {
    int i = blockIdx.x * 256 + threadIdx.x;
    if (i < N) {
        rowp[i] += boff[i >> 8];
        fill[i] = 0;
    }
}

__global__ void scatter_kernel(const int* __restrict__ ei, int E, int N,
                               const int* __restrict__ row_ptr,
                               int* __restrict__ fill, int* __restrict__ esrc) {
    int e = blockIdx.x * blockDim.x + threadIdx.x;
    if (e >= E + N) return;
    int s, d;
    if (e < E) { s = ei[e]; d = ei[E + e]; } else { s = e - E; d = e - E; }
    int pos = row_ptr[d] + atomicAdd(&fill[d], 1);
    esrc[pos] = s;
}

// h1(bf16) = x @ W1  (x: [N,128], W1: [128,64]); als/ald: [N,8]
__global__ __launch_bounds__(256) void gemm1_kernel(
    const float* __restrict__ x, const float* __restrict__ W,
    const float* __restrict__ a_src, const float* __restrict__ a_dst,
    __hip_bfloat16* __restrict__ h, float* __restrict__ als,
    float* __restrict__ ald, int N) {
    __shared__ float xs[4][128];
    int wave = threadIdx.x >> 6;
    int lane = threadIdx.x & 63;
    int n = blockIdx.x * 4 + wave;
    if (n < N) {
        const float2* xr = (const float2*)(x + (size_t)n * 128);
        ((float2*)xs[wave])[lane] = xr[lane];
    }
    __syncthreads();
    if (n >= N) return;
    const float* xw = xs[wave];
    float acc = 0.f;
#pragma unroll 4
    for (int k = 0; k < 128; ++k) acc += xw[k] * W[k * 64 + lane];
    h[(size_t)n * 64 + lane] = __float2bfloat16(acc);
    float ps = acc * a_src[lane];   // lane = hd*8 + c, a flat [8,8]
    float pd = acc * a_dst[lane];
    ps += __shfl_xor(ps, 1); ps += __shfl_xor(ps, 2); ps += __shfl_xor(ps, 4);
    pd += __shfl_xor(pd, 1); pd += __shfl_xor(pd, 2); pd += __shfl_xor(pd, 4);
    if ((lane & 7) == 0) {
        int hd = lane >> 3;
        als[n * 8 + hd] = ps;
        ald[n * 8 + hd] = pd;
    }
}

// h2(bf16) = hin @ W2  (hin: [N,64] f32, W2: [64,32]); al2: heads=8, C=4
__global__ __launch_bounds__(256) void gemm2_kernel(
    const float* __restrict__ hin, const float* __restrict__ W,
    const float* __restrict__ a_src, const float* __restrict__ a_dst,
    __hip_bfloat16* __restrict__ h2, float* __restrict__ als,
    float* __restrict__ ald, int N) {
    __shared__ float rows[8 * 64];
    __shared__ float Ws[64 * 32];
    int t = threadIdx.x;
    int nb = blockIdx.x * 8;
    for (int i = t; i < 64 * 32; i += 256) Ws[i] = W[i];
    int nload = N - nb; if (nload > 8) nload = 8;
    for (int i = t; i < nload * 64; i += 256) rows[i] = hin[(size_t)nb * 64 + i];
    __syncthreads();
    int g = t >> 5, l = t & 31;
    int n = nb + g;
    if (n >= N) return;
    float acc = 0.f;
#pragma unroll 8
    for (int k = 0; k < 64; ++k) acc += rows[g * 64 + k] * Ws[k * 32 + l];
    h2[(size_t)n * 32 + l] = __float2bfloat16(acc);
    float ps = acc * a_src[l];      // l = hd*4 + c, a flat [8,4]
    float pd = acc * a_dst[l];
    ps += __shfl_xor(ps, 1); ps += __shfl_xor(ps, 2);
    pd += __shfl_xor(pd, 1); pd += __shfl_xor(pd, 2);
    if ((l & 3) == 0) {
        int hd = l >> 2;
        als[n * 8 + hd] = ps;
        ald[n * 8 + hd] = pd;
    }
}

// leaky_relu(0.2): max(e, 0.2e) -- valid since slope in (0,1)
__device__ __forceinline__ float lrelu(float e) { return fmaxf(e, 0.2f * e); }

// Fused single-pass GAT aggregation, F=64 (one wave per node).
// Wave-uniform edge walk: src index scalarized -> SALU address math.
__global__ __launch_bounds__(256) void gat_agg64_kernel(
    const int* __restrict__ rowp, const int* __restrict__ esrc,
    const __hip_bfloat16* __restrict__ feat, const float* __restrict__ als,
    const float* __restrict__ ald_arr, const float* __restrict__ bias,
    float* __restrict__ out, int N) {
    const int lane = threadIdx.x & 63;
    const int hd = lane >> 3;                // C=8
    int n = blockIdx.x * 4 + (threadIdx.x >> 6);
    if (n >= N) return;
    float aldv = ald_arr[n * 8 + hd];
    int beg = rowp[n], end = rowp[n + 1];
    float a0 = 0.f, a1 = 0.f, a2 = 0.f, a3 = 0.f;
    float d0 = 0.f, d1 = 0.f, d2 = 0.f, d3 = 0.f;
    int i = beg;
    for (; i + 4 <= end; i += 4) {
        int s0 = __builtin_amdgcn_readfirstlane(esrc[i]);
        int s1 = __builtin_amdgcn_readfirstlane(esrc[i + 1]);
        int s2 = __builtin_amdgcn_readfirstlane(esrc[i + 2]);
        int s3 = __builtin_amdgcn_readfirstlane(esrc[i + 3]);
        float e0 = als[s0 * 8 + hd] + aldv;
        float e1 = als[s1 * 8 + hd] + aldv;
        float e2 = als[s2 * 8 + hd] + aldv;
        float e3 = als[s3 * 8 + hd] + aldv;
        float f0 = __bfloat162float(feat[(size_t)s0 * 64 + lane]);
        float f1 = __bfloat162float(feat[(size_t)s1 * 64 + lane]);
        float f2 = __bfloat162float(feat[(size_t)s2 * 64 + lane]);
        float f3 = __bfloat162float(feat[(size_t)s3 * 64 + lane]);
        float w0 = __expf(lrelu(e0));
        float w1 = __expf(lrelu(e1));
        float w2 = __expf(lrelu(e2));
        float w3 = __expf(lrelu(e3));
        d0 += w0; a0 += w0 * f0;
        d1 += w1; a1 += w1 * f1;
        d2 += w2; a2 += w2 * f2;
        d3 += w3; a3 += w3 * f3;
    }
    for (; i < end; ++i) {
        int s = __builtin_amdgcn_readfirstlane(esrc[i]);
        float w = __expf(lrelu(als[s * 8 + hd] + aldv));
        d0 += w;
        a0 += w * __bfloat162float(feat[(size_t)s * 64 + lane]);
    }
    float d = (d0 + d1) + (d2 + d3);
    float acc = (a0 + a1) + (a2 + a3);
    float o = acc / (d + 1e-16f) + bias[lane];
    o = (o > 0.f) ? o : (__expf(o) - 1.0f);   // ELU
    out[(size_t)n * 64 + lane] = o;
}

// Fused single-pass GAT aggregation, F=32 (two nodes per wave, C=4).
__global__ __launch_bounds__(256) void gat_agg32_kernel(
    const int* __restrict__ rowp, const int* __restrict__ esrc,
    const __hip_bfloat16* __restrict__ feat, const float* __restrict__ als,
    const float* __restrict__ ald_arr, const float* __restrict__ bias,
    float* __restrict__ out, int N) {
    const int lane = threadIdx.x & 63;
    const int sl = lane & 31;
    const int hd = sl >> 2;                  // C=4
    int n = (blockIdx.x * 4 + (threadIdx.x >> 6)) * 2 + (lane >> 5);
    bool valid = (n < N);
    int nn = valid ? n : 0;
    float aldv = ald_arr[nn * 8 + hd];
    int beg = rowp[nn];
    int end = valid ? rowp[nn + 1] : beg;
    float a0 = 0.f, a1 = 0.f, a2 = 0.f, a3 = 0.f;
    float d0 = 0.f, d1 = 0.f, d2 = 0.f, d3 = 0.f;
    int i = beg;
    for (; i + 4 <= end; i += 4) {
        int s0 = esrc[i], s1 = esrc[i + 1], s2 = esrc[i + 2], s3 = esrc[i + 3];
        float e0 = als[s0 * 8 + hd] + aldv;
        float e1 = als[s1 * 8 + hd] + aldv;
        float e2 = als[s2 * 8 + hd] + aldv;
        float e3 = als[s3 * 8 + hd] + aldv;
        float f0 = __bfloat162float(feat[(size_t)s0 * 32 + sl]);
        float f1 = __bfloat162float(feat[(size_t)s1 * 32 + sl]);
        float f2 = __bfloat162float(feat[(size_t)s2 * 32 + sl]);
        float f3 = __bfloat162float(feat[(size_t)s3 * 32 + sl]);
        float w0 = __expf(lrelu(e0));
        float w1 = __expf(lrelu(e1));
        float w2 = __expf(lrelu(e2));
        float w3 = __expf(lrelu(e3));
        d0 += w0; a0 += w0 * f0;
        d1 += w1; a1 += w1 * f1;
        d2 += w2; a2 += w2 * f2;
        d3 += w3; a3 += w3 * f3;
    }
    for (; i < end; ++i) {
        int s = esrc[i];
        float w = __expf(lrelu(als[s * 8 + hd] + aldv));
        d0 += w;
        a0 += w * __bfloat162float(feat[(size_t)s * 32 + sl]);
    }
    if (!valid) return;
    float d = (d0 + d1) + (d2 + d3);
    float acc = (a0 + a1) + (a2 + a3);
    float o = acc / (d + 1e-16f) + bias[sl];
    o = (o > 0.f) ? o : (__expf(o) - 1.0f);   // ELU
    out[(size_t)n * 32 + sl] = o;
}

// Fold v-proj (in_proj rows 64..95), out_proj, fc into M[16][32], bf[16]
__global__ __launch_bounds__(256) void fold_kernel(
    const float* __restrict__ in_proj_w, const float* __restrict__ in_proj_b,
    const float* __restrict__ out_proj_w, const float* __restrict__ out_proj_b,
    const float* __restrict__ fc_w, const float* __restrict__ fc_b,
    float* __restrict__ M, float* __restrict__ bf) {
    __shared__ float Wvo[32 * 32];
    __shared__ float bvo[32];
    const float* Wv = in_proj_w + 64 * 32;
    const float* bv = in_proj_b + 64;
    int t = threadIdx.x;
    for (int idx = t; idx < 1024; idx += 256) {
        int i = idx >> 5, j = idx & 31;
        float s = 0.f;
        for (int k = 0; k < 32; ++k) s += out_proj_w[i * 32 + k] * Wv[k * 32 + j];
        Wvo[idx] = s;
    }
    if (t < 32) {
        float s = 0.f;
        for (int k = 0; k < 32; ++k) s += out_proj_w[t * 32 + k] * bv[k];
        bvo[t] = s + out_proj_b[t];
    }
    __syncthreads();
    for (int idx = t; idx < 16 * 32; idx += 256) {
        int c = idx >> 5, j = idx & 31;
        float s = 0.f;
        for (int i = 0; i < 32; ++i) s += fc_w[c * 32 + i] * Wvo[i * 32 + j];
        M[idx] = s;
    }
    if (t < 16) {
        float s = 0.f;
        for (int i = 0; i < 32; ++i) s += fc_w[t * 32 + i] * bvo[i];
        bf[t] = s + fc_b[t];
    }
}

__global__ __launch_bounds__(256) void final_kernel(
    const float* __restrict__ h, const float* __restrict__ M,
    const float* __restrict__ bf, float* __restrict__ out, int N) {
    __shared__ float Ms[16 * 32];
    __shared__ float bfs[16];
    int t = threadIdx.x;
    for (int i = t; i < 512; i += 256) Ms[i] = M[i];
    if (t < 16) bfs[t] = bf[t];
    __syncthreads();
    int n = blockIdx.x * 256 + t;
    if (n >= N) return;
    float hv[32];
    const float4* hp = (const float4*)(h + (size_t)n * 32);
#pragma unroll
    for (int i = 0; i < 8; ++i) {
        float4 v = hp[i];
        hv[4 * i] = v.x; hv[4 * i + 1] = v.y; hv[4 * i + 2] = v.z; hv[4 * i + 3] = v.w;
    }
    float lg[16];
    float mx = -1e30f;
#pragma unroll
    for (int c = 0; c < 16; ++c) {
        float s = bfs[c];
#pragma unroll
        for (int j = 0; j < 32; ++j) s += Ms[c * 32 + j] * hv[j];
        lg[c] = s;
        mx = fmaxf(mx, s);
    }
    float se = 0.f;
#pragma unroll
    for (int c = 0; c < 16; ++c) se += __expf(lg[c] - mx);
    float lse = mx + __logf(se);
    float4* op = (float4*)(out + (size_t)n * 16);
#pragma unroll
    for (int i = 0; i < 4; ++i)
        op[i] = make_float4(lg[4 * i] - lse, lg[4 * i + 1] - lse,
                            lg[4 * i + 2] - lse, lg[4 * i + 3] - lse);
}

extern "C" void kernel_launch(void* const* d_in, const int* in_sizes, int n_in,
                              void* d_out, int out_size, void* d_ws, size_t ws_size,
                              hipStream_t stream) {
    const float* x   = (const float*)d_in[0];
    const int*   ei  = (const int*)d_in[1];
    const float* W1  = (const float*)d_in[2];
    const float* a1s = (const float*)d_in[3];
    const float* a1d = (const float*)d_in[4];
    const float* b1  = (const float*)d_in[5];
    const float* W2  = (const float*)d_in[6];
    const float* a2s = (const float*)d_in[7];
    const float* a2d = (const float*)d_in[8];
    const float* b2  = (const float*)d_in[9];
    const float* ipw = (const float*)d_in[10];
    const float* ipb = (const float*)d_in[11];
    const float* opw = (const float*)d_in[12];
    const float* opb = (const float*)d_in[13];
    const float* fcw = (const float*)d_in[14];
    const float* fcb = (const float*)d_in[15];
    float* out = (float*)d_out;

    int N = in_sizes[0] / 128;
    int E = in_sizes[1] / 2;
    int Et = E + N;
    int B = (N + 255) / 256;   // scan blocks (<=256 for N<=65536)

    char* ws = (char*)d_ws;
    size_t off = 0;
    auto alloc = [&](size_t bytes) -> void* {
        void* p = ws + off;
        off += bytes;
        off = (off + 255) & ~(size_t)255;
        return p;
    };
    int*   fill  = (int*)alloc((size_t)N * 4);
    int*   rowp  = (int*)alloc((size_t)(N + 1) * 4);
    int*   esrc  = (int*)alloc((size_t)Et * 4);
    int*   bsum  = (int*)alloc(256 * 4);
    int*   boff  = (int*)alloc(256 * 4);
    __hip_bfloat16* h1 = (__hip_bfloat16*)alloc((size_t)N * 64 * 2);
    float* al1s  = (float*)alloc((size_t)N * 8 * 4);
    float* al1d  = (float*)alloc((size_t)N * 8 * 4);
    float* hout1 = (float*)alloc((size_t)N * 64 * 4);
    __hip_bfloat16* h2 = (__hip_bfloat16*)alloc((size_t)N * 32 * 2);
    float* al2s  = (float*)alloc((size_t)N * 8 * 4);
    float* al2d  = (float*)alloc((size_t)N * 8 * 4);
    float* out2  = (float*)alloc((size_t)N * 32 * 4);
    float* Mf    = (float*)alloc(512 * 4);
    float* bff   = (float*)alloc(16 * 4);
    (void)ws_size; (void)n_in; (void)out_size;

    const int tb = 256;
    hipMemsetAsync(fill, 0, (size_t)N * 4, stream);
    count_kernel<<<(Et + tb - 1) / tb, tb, 0, stream>>>(ei, E, N, fill);
    scan1_kernel<<<B, 256, 0, stream>>>(fill, rowp, bsum, N);
    scan2_kernel<<<1, 256, 0, stream>>>(bsum, boff, rowp, B, N);
    scan3_kernel<<<B, 256, 0, stream>>>(rowp, boff, fill, N);
    scatter_kernel<<<(Et + tb - 1) / tb, tb, 0, stream>>>(ei, E, N, rowp, fill, esrc);

    gemm1_kernel<<<(N + 3) / 4, 256, 0, stream>>>(x, W1, a1s, a1d, h1, al1s, al1d, N);
    fold_kernel<<<1, 256, 0, stream>>>(ipw, ipb, opw, opb, fcw, fcb, Mf, bff);
    gat_agg64_kernel<<<(N + 3) / 4, 256, 0, stream>>>(
        rowp, esrc, h1, al1s, al1d, b1, hout1, N);
    gemm2_kernel<<<(N + 7) / 8, 256, 0, stream>>>(hout1, W2, a2s, a2d, h2, al2s, al2d, N);
    gat_agg32_kernel<<<(N + 7) / 8, 256, 0, stream>>>(
        rowp, esrc, h2, al2s, al2d, b2, out2, N);
    final_kernel<<<(N + 255) / 256, 256, 0, stream>>>(out2, Mf, bff, out, N);
}

// Round 5
// 338.613 us; speedup vs baseline: 2.2565x; 1.3831x over previous
//
#include <hip/hip_runtime.h>
#include <hip/hip_bf16.h>
#include <math.h>

// ---------------------------------------------------------------------------
// GAT x2 + folded (v-proj -> out-proj -> fc) + log_softmax
//   CSR build: bucket-binning (128-node buckets) -> all scattered writes land
//   in L2-resident windows (kills the 16x cacheline write amplification the
//   old count/scatter pair paid). esrc is uint16 (N < 65536).
//   gemm1: h1(bf16) = x @ W1, al1_s/al1_d       (wave per node)
//   gat_agg64: fused single-pass softmax-aggregate (no max: |e|<~3 -> exp
//              safe in fp32; alpha = exp(e)/sum exp(e) is max-invariant),
//              wave-uniform edge walk, readfirstlane-scalarized addresses.
//   gemm2: h2(bf16) = hout1 @ W2 ; gat_agg32: 2 nodes/wave
//   fold:  M = fc . Wo . Wv (16x32) ; final: matvec + log_softmax
// ---------------------------------------------------------------------------

#define BSHIFT 7                  // 128 nodes per bucket
#define BMASK  ((1 << BSHIFT) - 1)
#define MAXNB  512                // supports N up to 65536
#define TILE   8192               // edges per binning block

// A: per-bucket edge counts via LDS histogram
__global__ __launch_bounds__(256) void bin_count_kernel(
    const int* __restrict__ ei, int E, int Et, int NB,
    int* __restrict__ bcount) {
    __shared__ int h[MAXNB];
    for (int i = threadIdx.x; i < NB; i += 256) h[i] = 0;
    __syncthreads();
    int tile0 = blockIdx.x * TILE;
    int jend = tile0 + TILE; if (jend > Et) jend = Et;
    for (int j = tile0 + threadIdx.x; j < jend; j += 256) {
        int d = (j < E) ? ei[E + j] : (j - E);
        atomicAdd(&h[d >> BSHIFT], 1);
    }
    __syncthreads();
    for (int i = threadIdx.x; i < NB; i += 256)
        if (h[i]) atomicAdd(&bcount[i], h[i]);
}

// B: exclusive scan of bucket counts -> bases; init global cursors
__global__ __launch_bounds__(512) void bucket_scan_kernel(
    const int* __restrict__ bcount, int* __restrict__ bbase,
    int* __restrict__ gcur, int NB) {
    __shared__ int s[512];
    int t = threadIdx.x;
    int v = (t < NB) ? bcount[t] : 0;
    s[t] = v;
    __syncthreads();
    for (int off = 1; off < 512; off <<= 1) {
        int u = (t >= off) ? s[t - off] : 0;
        __syncthreads();
        s[t] += u;
        __syncthreads();
    }
    if (t < NB) { int b = s[t] - v; bbase[t] = b; gcur[t] = b; }
}

// C: bin edges into bucket-major record array. Per block: LDS histogram,
// one global atomicAdd per bucket to reserve a contiguous run, then write
// packed records src(16b) | dlow7(<<16) into the runs.
__global__ __launch_bounds__(256) void bin_scatter_kernel(
    const int* __restrict__ ei, int E, int Et, int NB,
    int* __restrict__ gcur, unsigned int* __restrict__ rec) {
    __shared__ int h[MAXNB];
    __shared__ int cur[MAXNB];
    for (int i = threadIdx.x; i < NB; i += 256) h[i] = 0;
    __syncthreads();
    int tile0 = blockIdx.x * TILE;
    int jend = tile0 + TILE; if (jend > Et) jend = Et;
    for (int j = tile0 + threadIdx.x; j < jend; j += 256) {
        int d = (j < E) ? ei[E + j] : (j - E);
        atomicAdd(&h[d >> BSHIFT], 1);
    }
    __syncthreads();
    for (int i = threadIdx.x; i < NB; i += 256)
        cur[i] = atomicAdd(&gcur[i], h[i]);
    __syncthreads();
    for (int j = tile0 + threadIdx.x; j < jend; j += 256) {
        int srcv, d;
        if (j < E) { srcv = ei[j]; d = ei[E + j]; } else { srcv = j - E; d = j - E; }
        int b = d >> BSHIFT;
        int pos = atomicAdd(&cur[b], 1);
        rec[pos] = (unsigned)srcv | ((unsigned)(d & BMASK) << 16);
    }
}

// D: one block per bucket -> local histogram + scan gives rowp directly;
// scatter src(uint16) within the bucket's contiguous (L2-resident) window.
__global__ __launch_bounds__(256) void csr_finalize_kernel(
    const unsigned int* __restrict__ rec, const int* __restrict__ bcount,
    const int* __restrict__ bbase, int* __restrict__ rowp,
    unsigned short* __restrict__ esrc, int N, int Et) {
    __shared__ int h[128];
    __shared__ int nb[128];
    __shared__ int cur[128];
    int b = blockIdx.x, t = threadIdx.x;
    int base = bbase[b], cnt = bcount[b];
    if (t < 128) h[t] = 0;
    __syncthreads();
    for (int i = t; i < cnt; i += 256)
        atomicAdd(&h[(rec[base + i] >> 16) & 127], 1);
    __syncthreads();
    if (t == 0) {
        int run = base;
        for (int i = 0; i < 128; ++i) { nb[i] = run; run += h[i]; }
    }
    __syncthreads();
    if (t < 128) cur[t] = nb[t];
    int n0 = b << BSHIFT;
    if (t < 128 && n0 + t < N) rowp[n0 + t] = nb[t];
    if (b == 0 && t == 0) rowp[N] = Et;
    __syncthreads();
    for (int i = t; i < cnt; i += 256) {
        unsigned r = rec[base + i];
        int pos = atomicAdd(&cur[(r >> 16) & 127], 1);
        esrc[pos] = (unsigned short)(r & 0xFFFFu);
    }
}

// h1(bf16) = x @ W1  (x: [N,128], W1: [128,64]); als/ald: [N,8]
__global__ __launch_bounds__(256) void gemm1_kernel(
    const float* __restrict__ x, const float* __restrict__ W,
    const float* __restrict__ a_src, const float* __restrict__ a_dst,
    __hip_bfloat16* __restrict__ h, float* __restrict__ als,
    float* __restrict__ ald, int N) {
    __shared__ float xs[4][128];
    int wave = threadIdx.x >> 6;
    int lane = threadIdx.x & 63;
    int n = blockIdx.x * 4 + wave;
    if (n < N) {
        const float2* xr = (const float2*)(x + (size_t)n * 128);
        ((float2*)xs[wave])[lane] = xr[lane];
    }
    __syncthreads();
    if (n >= N) return;
    const float* xw = xs[wave];
    float acc = 0.f;
#pragma unroll 4
    for (int k = 0; k < 128; ++k) acc += xw[k] * W[k * 64 + lane];
    h[(size_t)n * 64 + lane] = __float2bfloat16(acc);
    float ps = acc * a_src[lane];   // lane = hd*8 + c, a flat [8,8]
    float pd = acc * a_dst[lane];
    ps += __shfl_xor(ps, 1); ps += __shfl_xor(ps, 2); ps += __shfl_xor(ps, 4);
    pd += __shfl_xor(pd, 1); pd += __shfl_xor(pd, 2); pd += __shfl_xor(pd, 4);
    if ((lane & 7) == 0) {
        int hd = lane >> 3;
        als[n * 8 + hd] = ps;
        ald[n * 8 + hd] = pd;
    }
}

// h2(bf16) = hin @ W2  (hin: [N,64] f32, W2: [64,32]); al2: heads=8, C=4
__global__ __launch_bounds__(256) void gemm2_kernel(
    const float* __restrict__ hin, const float* __restrict__ W,
    const float* __restrict__ a_src, const float* __restrict__ a_dst,
    __hip_bfloat16* __restrict__ h2, float* __restrict__ als,
    float* __restrict__ ald, int N) {
    __shared__ float rows[8 * 64];
    __shared__ float Ws[64 * 32];
    int t = threadIdx.x;
    int nb = blockIdx.x * 8;
    for (int i = t; i < 64 * 32; i += 256) Ws[i] = W[i];
    int nload = N - nb; if (nload > 8) nload = 8;
    for (int i = t; i < nload * 64; i += 256) rows[i] = hin[(size_t)nb * 64 + i];
    __syncthreads();
    int g = t >> 5, l = t & 31;
    int n = nb + g;
    if (n >= N) return;
    float acc = 0.f;
#pragma unroll 8
    for (int k = 0; k < 64; ++k) acc += rows[g * 64 + k] * Ws[k * 32 + l];
    h2[(size_t)n * 32 + l] = __float2bfloat16(acc);
    float ps = acc * a_src[l];      // l = hd*4 + c, a flat [8,4]
    float pd = acc * a_dst[l];
    ps += __shfl_xor(ps, 1); ps += __shfl_xor(ps, 2);
    pd += __shfl_xor(pd, 1); pd += __shfl_xor(pd, 2);
    if ((l & 3) == 0) {
        int hd = l >> 2;
        als[n * 8 + hd] = ps;
        ald[n * 8 + hd] = pd;
    }
}

// leaky_relu(0.2): max(e, 0.2e) -- valid since slope in (0,1)
__device__ __forceinline__ float lrelu(float e) { return fmaxf(e, 0.2f * e); }

// Fused single-pass GAT aggregation, F=64 (one wave per node).
__global__ __launch_bounds__(256) void gat_agg64_kernel(
    const int* __restrict__ rowp, const unsigned short* __restrict__ esrc,
    const __hip_bfloat16* __restrict__ feat, const float* __restrict__ als,
    const float* __restrict__ ald_arr, const float* __restrict__ bias,
    float* __restrict__ out, int N) {
    const int lane = threadIdx.x & 63;
    const int hd = lane >> 3;                // C=8
    int n = blockIdx.x * 4 + (threadIdx.x >> 6);
    if (n >= N) return;
    float aldv = ald_arr[n * 8 + hd];
    int beg = rowp[n], end = rowp[n + 1];
    float a0 = 0.f, a1 = 0.f, a2 = 0.f, a3 = 0.f;
    float d0 = 0.f, d1 = 0.f, d2 = 0.f, d3 = 0.f;
    int i = beg;
    for (; i + 4 <= end; i += 4) {
        int s0 = __builtin_amdgcn_readfirstlane((int)esrc[i]);
        int s1 = __builtin_amdgcn_readfirstlane((int)esrc[i + 1]);
        int s2 = __builtin_amdgcn_readfirstlane((int)esrc[i + 2]);
        int s3 = __builtin_amdgcn_readfirstlane((int)esrc[i + 3]);
        float e0 = als[s0 * 8 + hd] + aldv;
        float e1 = als[s1 * 8 + hd] + aldv;
        float e2 = als[s2 * 8 + hd] + aldv;
        float e3 = als[s3 * 8 + hd] + aldv;
        float f0 = __bfloat162float(feat[(size_t)s0 * 64 + lane]);
        float f1 = __bfloat162float(feat[(size_t)s1 * 64 + lane]);
        float f2 = __bfloat162float(feat[(size_t)s2 * 64 + lane]);
        float f3 = __bfloat162float(feat[(size_t)s3 * 64 + lane]);
        float w0 = __expf(lrelu(e0));
        float w1 = __expf(lrelu(e1));
        float w2 = __expf(lrelu(e2));
        float w3 = __expf(lrelu(e3));
        d0 += w0; a0 += w0 * f0;
        d1 += w1; a1 += w1 * f1;
        d2 += w2; a2 += w2 * f2;
        d3 += w3; a3 += w3 * f3;
    }
    for (; i < end; ++i) {
        int s = __builtin_amdgcn_readfirstlane((int)esrc[i]);
        float w = __expf(lrelu(als[s * 8 + hd] + aldv));
        d0 += w;
        a0 += w * __bfloat162float(feat[(size_t)s * 64 + lane]);
    }
    float d = (d0 + d1) + (d2 + d3);
    float acc = (a0 + a1) + (a2 + a3);
    float o = acc / (d + 1e-16f) + bias[lane];
    o = (o > 0.f) ? o : (__expf(o) - 1.0f);   // ELU
    out[(size_t)n * 64 + lane] = o;
}

// Fused single-pass GAT aggregation, F=32 (two nodes per wave, C=4).
__global__ __launch_bounds__(256) void gat_agg32_kernel(
    const int* __restrict__ rowp, const unsigned short* __restrict__ esrc,
    const __hip_bfloat16* __restrict__ feat, const float* __restrict__ als,
    const float* __restrict__ ald_arr, const float* __restrict__ bias,
    float* __restrict__ out, int N) {
    const int lane = threadIdx.x & 63;
    const int sl = lane & 31;
    const int hd = sl >> 2;                  // C=4
    int n = (blockIdx.x * 4 + (threadIdx.x >> 6)) * 2 + (lane >> 5);
    bool valid = (n < N);
    int nn = valid ? n : 0;
    float aldv = ald_arr[nn * 8 + hd];
    int beg = rowp[nn];
    int end = valid ? rowp[nn + 1] : beg;
    float a0 = 0.f, a1 = 0.f, a2 = 0.f, a3 = 0.f;
    float d0 = 0.f, d1 = 0.f, d2 = 0.f, d3 = 0.f;
    int i = beg;
    for (; i + 4 <= end; i += 4) {
        int s0 = esrc[i], s1 = esrc[i + 1], s2 = esrc[i + 2], s3 = esrc[i + 3];
        float e0 = als[s0 * 8 + hd] + aldv;
        float e1 = als[s1 * 8 + hd] + aldv;
        float e2 = als[s2 * 8 + hd] + aldv;
        float e3 = als[s3 * 8 + hd] + aldv;
        float f0 = __bfloat162float(feat[(size_t)s0 * 32 + sl]);
        float f1 = __bfloat162float(feat[(size_t)s1 * 32 + sl]);
        float f2 = __bfloat162float(feat[(size_t)s2 * 32 + sl]);
        float f3 = __bfloat162float(feat[(size_t)s3 * 32 + sl]);
        float w0 = __expf(lrelu(e0));
        float w1 = __expf(lrelu(e1));
        float w2 = __expf(lrelu(e2));
        float w3 = __expf(lrelu(e3));
        d0 += w0; a0 += w0 * f0;
        d1 += w1; a1 += w1 * f1;
        d2 += w2; a2 += w2 * f2;
        d3 += w3; a3 += w3 * f3;
    }
    for (; i < end; ++i) {
        int s = esrc[i];
        float w = __expf(lrelu(als[s * 8 + hd] + aldv));
        d0 += w;
        a0 += w * __bfloat162float(feat[(size_t)s * 32 + sl]);
    }
    if (!valid) return;
    float d = (d0 + d1) + (d2 + d3);
    float acc = (a0 + a1) + (a2 + a3);
    float o = acc / (d + 1e-16f) + bias[sl];
    o = (o > 0.f) ? o : (__expf(o) - 1.0f);   // ELU
    out[(size_t)n * 32 + sl] = o;
}

// Fold v-proj (in_proj rows 64..95), out_proj, fc into M[16][32], bf[16]
__global__ __launch_bounds__(256) void fold_kernel(
    const float* __restrict__ in_proj_w, const float* __restrict__ in_proj_b,
    const float* __restrict__ out_proj_w, const float* __restrict__ out_proj_b,
    const float* __restrict__ fc_w, const float* __restrict__ fc_b,
    float* __restrict__ M, float* __restrict__ bf) {
    __shared__ float Wvo[32 * 32];
    __shared__ float bvo[32];
    const float* Wv = in_proj_w + 64 * 32;
    const float* bv = in_proj_b + 64;
    int t = threadIdx.x;
    for (int idx = t; idx < 1024; idx += 256) {
        int i = idx >> 5, j = idx & 31;
        float s = 0.f;
        for (int k = 0; k < 32; ++k) s += out_proj_w[i * 32 + k] * Wv[k * 32 + j];
        Wvo[idx] = s;
    }
    if (t < 32) {
        float s = 0.f;
        for (int k = 0; k < 32; ++k) s += out_proj_w[t * 32 + k] * bv[k];
        bvo[t] = s + out_proj_b[t];
    }
    __syncthreads();
    for (int idx = t; idx < 16 * 32; idx += 256) {
        int c = idx >> 5, j = idx & 31;
        float s = 0.f;
        for (int i = 0; i < 32; ++i) s += fc_w[c * 32 + i] * Wvo[i * 32 + j];
        M[idx] = s;
    }
    if (t < 16) {
        float s = 0.f;
        for (int i = 0; i < 32; ++i) s += fc_w[t * 32 + i] * bvo[i];
        bf[t] = s + fc_b[t];
    }
}

__global__ __launch_bounds__(256) void final_kernel(
    const float* __restrict__ h, const float* __restrict__ M,
    const float* __restrict__ bf, float* __restrict__ out, int N) {
    __shared__ float Ms[16 * 32];
    __shared__ float bfs[16];
    int t = threadIdx.x;
    for (int i = t; i < 512; i += 256) Ms[i] = M[i];
    if (t < 16) bfs[t] = bf[t];
    __syncthreads();
    int n = blockIdx.x * 256 + t;
    if (n >= N) return;
    float hv[32];
    const float4* hp = (const float4*)(h + (size_t)n * 32);
#pragma unroll
    for (int i = 0; i < 8; ++i) {
        float4 v = hp[i];
        hv[4 * i] = v.x; hv[4 * i + 1] = v.y; hv[4 * i + 2] = v.z; hv[4 * i + 3] = v.w;
    }
    float lg[16];
    float mx = -1e30f;
#pragma unroll
    for (int c = 0; c < 16; ++c) {
        float s = bfs[c];
#pragma unroll
        for (int j = 0; j < 32; ++j) s += Ms[c * 32 + j] * hv[j];
        lg[c] = s;
        mx = fmaxf(mx, s);
    }
    float se = 0.f;
#pragma unroll
    for (int c = 0; c < 16; ++c) se += __expf(lg[c] - mx);
    float lse = mx + __logf(se);
    float4* op = (float4*)(out + (size_t)n * 16);
#pragma unroll
    for (int i = 0; i < 4; ++i)
        op[i] = make_float4(lg[4 * i] - lse, lg[4 * i + 1] - lse,
                            lg[4 * i + 2] - lse, lg[4 * i + 3] - lse);
}

extern "C" void kernel_launch(void* const* d_in, const int* in_sizes, int n_in,
                              void* d_out, int out_size, void* d_ws, size_t ws_size,
                              hipStream_t stream) {
    const float* x   = (const float*)d_in[0];
    const int*   ei  = (const int*)d_in[1];
    const float* W1  = (const float*)d_in[2];
    const float* a1s = (const float*)d_in[3];
    const float* a1d = (const float*)d_in[4];
    const float* b1  = (const float*)d_in[5];
    const float* W2  = (const float*)d_in[6];
    const float* a2s = (const float*)d_in[7];
    const float* a2d = (const float*)d_in[8];
    const float* b2  = (const float*)d_in[9];
    const float* ipw = (const float*)d_in[10];
    const float* ipb = (const float*)d_in[11];
    const float* opw = (const float*)d_in[12];
    const float* opb = (const float*)d_in[13];
    const float* fcw = (const float*)d_in[14];
    const float* fcb = (const float*)d_in[15];
    float* out = (float*)d_out;

    int N = in_sizes[0] / 128;
    int E = in_sizes[1] / 2;
    int Et = E + N;
    int NB = (N + BMASK) >> BSHIFT;          // buckets (<=512 for N<=65536)
    int NTILES = (Et + TILE - 1) / TILE;

    char* ws = (char*)d_ws;
    size_t off = 0;
    auto alloc = [&](size_t bytes) -> void* {
        void* p = ws + off;
        off += bytes;
        off = (off + 255) & ~(size_t)255;
        return p;
    };
    int*   bcount = (int*)alloc(MAXNB * 4);
    int*   bbase  = (int*)alloc(MAXNB * 4);
    int*   gcur   = (int*)alloc(MAXNB * 4);
    unsigned int*   rec  = (unsigned int*)alloc((size_t)Et * 4);
    int*   rowp   = (int*)alloc((size_t)(N + 1) * 4);
    unsigned short* esrc = (unsigned short*)alloc((size_t)Et * 2);
    __hip_bfloat16* h1 = (__hip_bfloat16*)alloc((size_t)N * 64 * 2);
    float* al1s  = (float*)alloc((size_t)N * 8 * 4);
    float* al1d  = (float*)alloc((size_t)N * 8 * 4);
    float* hout1 = (float*)alloc((size_t)N * 64 * 4);
    __hip_bfloat16* h2 = (__hip_bfloat16*)alloc((size_t)N * 32 * 2);
    float* al2s  = (float*)alloc((size_t)N * 8 * 4);
    float* al2d  = (float*)alloc((size_t)N * 8 * 4);
    float* out2  = (float*)alloc((size_t)N * 32 * 4);
    float* Mf    = (float*)alloc(512 * 4);
    float* bff   = (float*)alloc(16 * 4);
    (void)ws_size; (void)n_in; (void)out_size;

    hipMemsetAsync(bcount, 0, MAXNB * 4, stream);
    bin_count_kernel<<<NTILES, 256, 0, stream>>>(ei, E, Et, NB, bcount);
    bucket_scan_kernel<<<1, 512, 0, stream>>>(bcount, bbase, gcur, NB);
    bin_scatter_kernel<<<NTILES, 256, 0, stream>>>(ei, E, Et, NB, gcur, rec);
    csr_finalize_kernel<<<NB, 256, 0, stream>>>(rec, bcount, bbase, rowp, esrc, N, Et);

    gemm1_kernel<<<(N + 3) / 4, 256, 0, stream>>>(x, W1, a1s, a1d, h1, al1s, al1d, N);
    fold_kernel<<<1, 256, 0, stream>>>(ipw, ipb, opw, opb, fcw, fcb, Mf, bff);
    gat_agg64_kernel<<<(N + 3) / 4, 256, 0, stream>>>(
        rowp, esrc, h1, al1s, al1d, b1, hout1, N);
    gemm2_kernel<<<(N + 7) / 8, 256, 0, stream>>>(hout1, W2, a2s, a2d, h2, al2s, al2d, N);
    gat_agg32_kernel<<<(N + 7) / 8, 256, 0, stream>>>(
        rowp, esrc, h2, al2s, al2d, b2, out2, N);
    final_kernel<<<(N + 255) / 256, 256, 0, stream>>>(out2, Mf, bff, out, N);
}

// Round 6
// 271.400 us; speedup vs baseline: 2.8153x; 1.2477x over previous
//
#include <hip/hip_runtime.h>
#include <hip/hip_bf16.h>
#include <math.h>

// ---------------------------------------------------------------------------
// GAT x2 + folded (v-proj -> out-proj -> fc) + log_softmax
//   CSR build: bucket-binning (128-node buckets), esrc uint16.
//   gemm1: MFMA bf16 16x16x32, 64x64 block tile, LDS-staged x/W^T (+8 pad)
//   gat_agg64/32: fused single-pass softmax-aggregate, 2 edges per wave-iter
//                 (bf16x2 per lane), unroll x4 pairs for MLP.
//   gemm2: VALU (small) ; fold: M = fc.Wo.Wv ; final: matvec + log_softmax
// ---------------------------------------------------------------------------

#define BSHIFT 7
#define BMASK  ((1 << BSHIFT) - 1)
#define MAXNB  512
#define TILE   8192
#define XST    136   // LDS row stride (bf16 elems) for 128-col tiles, 16B-aligned

typedef __attribute__((ext_vector_type(8))) short short8;
typedef __attribute__((ext_vector_type(4))) float floatx4;

__device__ __forceinline__ unsigned short f2bf(float f) {
    union { float f; unsigned int u; } v; v.f = f;
    unsigned int u = v.u;
    return (unsigned short)((u + 0x7FFFu + ((u >> 16) & 1u)) >> 16);  // RNE
}
__device__ __forceinline__ float bfl2f(unsigned int p) {   // low bf16 of pair
    return __uint_as_float(p << 16);
}
__device__ __forceinline__ float bfh2f(unsigned int p) {   // high bf16 of pair
    return __uint_as_float(p & 0xFFFF0000u);
}
__device__ __forceinline__ float lrelu(float e) { return fmaxf(e, 0.2f * e); }

// ---------------- CSR build (bucket binning) ----------------
__global__ __launch_bounds__(256) void bin_count_kernel(
    const int* __restrict__ ei, int E, int Et, int NB,
    int* __restrict__ bcount) {
    __shared__ int h[MAXNB];
    for (int i = threadIdx.x; i < NB; i += 256) h[i] = 0;
    __syncthreads();
    int tile0 = blockIdx.x * TILE;
    int jend = tile0 + TILE; if (jend > Et) jend = Et;
    for (int j = tile0 + threadIdx.x; j < jend; j += 256) {
        int d = (j < E) ? ei[E + j] : (j - E);
        atomicAdd(&h[d >> BSHIFT], 1);
    }
    __syncthreads();
    for (int i = threadIdx.x; i < NB; i += 256)
        if (h[i]) atomicAdd(&bcount[i], h[i]);
}

__global__ __launch_bounds__(512) void bucket_scan_kernel(
    const int* __restrict__ bcount, int* __restrict__ bbase,
    int* __restrict__ gcur, int NB) {
    __shared__ int s[512];
    int t = threadIdx.x;
    int v = (t < NB) ? bcount[t] : 0;
    s[t] = v;
    __syncthreads();
    for (int off = 1; off < 512; off <<= 1) {
        int u = (t >= off) ? s[t - off] : 0;
        __syncthreads();
        s[t] += u;
        __syncthreads();
    }
    if (t < NB) { int b = s[t] - v; bbase[t] = b; gcur[t] = b; }
}

__global__ __launch_bounds__(256) void bin_scatter_kernel(
    const int* __restrict__ ei, int E, int Et, int NB,
    int* __restrict__ gcur, unsigned int* __restrict__ rec) {
    __shared__ int h[MAXNB];
    __shared__ int cur[MAXNB];
    for (int i = threadIdx.x; i < NB; i += 256) h[i] = 0;
    __syncthreads();
    int tile0 = blockIdx.x * TILE;
    int jend = tile0 + TILE; if (jend > Et) jend = Et;
    for (int j = tile0 + threadIdx.x; j < jend; j += 256) {
        int d = (j < E) ? ei[E + j] : (j - E);
        atomicAdd(&h[d >> BSHIFT], 1);
    }
    __syncthreads();
    for (int i = threadIdx.x; i < NB; i += 256)
        cur[i] = atomicAdd(&gcur[i], h[i]);
    __syncthreads();
    for (int j = tile0 + threadIdx.x; j < jend; j += 256) {
        int srcv, d;
        if (j < E) { srcv = ei[j]; d = ei[E + j]; } else { srcv = j - E; d = j - E; }
        int b = d >> BSHIFT;
        int pos = atomicAdd(&cur[b], 1);
        rec[pos] = (unsigned)srcv | ((unsigned)(d & BMASK) << 16);
    }
}

__global__ __launch_bounds__(256) void csr_finalize_kernel(
    const unsigned int* __restrict__ rec, const int* __restrict__ bcount,
    const int* __restrict__ bbase, int* __restrict__ rowp,
    unsigned short* __restrict__ esrc, int N, int Et) {
    __shared__ int h[128];
    __shared__ int nb[128];
    __shared__ int cur[128];
    int b = blockIdx.x, t = threadIdx.x;
    int base = bbase[b], cnt = bcount[b];
    if (t < 128) h[t] = 0;
    __syncthreads();
    for (int i = t; i < cnt; i += 256)
        atomicAdd(&h[(rec[base + i] >> 16) & 127], 1);
    __syncthreads();
    if (t == 0) {
        int run = base;
        for (int i = 0; i < 128; ++i) { nb[i] = run; run += h[i]; }
    }
    __syncthreads();
    if (t < 128) cur[t] = nb[t];
    int n0 = b << BSHIFT;
    if (t < 128 && n0 + t < N) rowp[n0 + t] = nb[t];
    if (b == 0 && t == 0) rowp[N] = Et;
    __syncthreads();
    for (int i = t; i < cnt; i += 256) {
        unsigned r = rec[base + i];
        int pos = atomicAdd(&cur[(r >> 16) & 127], 1);
        esrc[pos] = (unsigned short)(r & 0xFFFFu);
    }
}

// ---------------- gemm1 via MFMA ----------------
// h1 = x @ W1 (x:[N,128] f32 -> bf16, W1:[128,64] -> W^T bf16 in LDS)
// block: 256 thr = 4 waves, tile 64 nodes x 64 cols; wave w: nodes 16w..16w+15
__global__ __launch_bounds__(256) void gemm1_mfma_kernel(
    const float* __restrict__ x, const float* __restrict__ W,
    const float* __restrict__ a_src, const float* __restrict__ a_dst,
    __hip_bfloat16* __restrict__ h, float* __restrict__ als,
    float* __restrict__ ald, int N) {
    __shared__ __align__(16) unsigned short xs[64 * XST];
    __shared__ __align__(16) unsigned short wt[64 * XST];
    int t = threadIdx.x;
    int nb = blockIdx.x * 64;
    // stage x tile (64x128 f32 -> bf16), coalesced float4
#pragma unroll
    for (int r = 0; r < 8; ++r) {
        int p = t + 256 * r;             // float4 index within tile (2048 total)
        int row = p >> 5;                // 32 float4 per row
        int c4  = p & 31;
        int n = nb + row;
        float4 v = (n < N) ? ((const float4*)x)[(size_t)n * 32 + c4]
                           : make_float4(0.f, 0.f, 0.f, 0.f);
        unsigned short* dst = &xs[row * XST + c4 * 4];
        dst[0] = f2bf(v.x); dst[1] = f2bf(v.y);
        dst[2] = f2bf(v.z); dst[3] = f2bf(v.w);
    }
    // stage W transposed: wt[n][k], n=0..63, k=0..127
    {
        int n = t & 63, kg = t >> 6;
#pragma unroll
        for (int c = 0; c < 4; ++c) {
            int k0 = kg * 32 + c * 8;
            unsigned short* dst = &wt[n * XST + k0];
#pragma unroll
            for (int j = 0; j < 8; ++j)
                dst[j] = f2bf(W[(k0 + j) * 64 + n]);
        }
    }
    __syncthreads();
    int wave = t >> 6, lane = t & 63;
    int m16 = lane & 15, quad = lane >> 4;
    floatx4 acc[4];
#pragma unroll
    for (int i = 0; i < 4; ++i) acc[i] = (floatx4){0.f, 0.f, 0.f, 0.f};
#pragma unroll
    for (int k = 0; k < 4; ++k) {
        int koff = k * 32 + quad * 8;
        short8 afrag = *(const short8*)&xs[(wave * 16 + m16) * XST + koff];
#pragma unroll
        for (int nt = 0; nt < 4; ++nt) {
            short8 bfrag = *(const short8*)&wt[(nt * 16 + m16) * XST + koff];
            acc[nt] = __builtin_amdgcn_mfma_f32_16x16x32_bf16(afrag, bfrag, acc[nt], 0, 0, 0);
        }
    }
    __syncthreads();                       // xs region now reusable
    float* hs = (float*)xs;                // [64][65]
#pragma unroll
    for (int nt = 0; nt < 4; ++nt)
#pragma unroll
        for (int r = 0; r < 4; ++r)
            hs[(wave * 16 + quad * 4 + r) * 65 + nt * 16 + m16] = acc[nt][r];
    __syncthreads();
    // epilogue: wave w handles its 16 nodes; lane = col (= hd*8 + c)
    float asv = a_src[lane], adv = a_dst[lane];
    for (int itn = 0; itn < 16; ++itn) {
        int nl = wave * 16 + itn;
        int n = nb + nl;
        if (n >= N) break;
        float v = hs[nl * 65 + lane];
        h[(size_t)n * 64 + lane] = __float2bfloat16(v);
        float ps = v * asv, pd = v * adv;
        ps += __shfl_xor(ps, 1); ps += __shfl_xor(ps, 2); ps += __shfl_xor(ps, 4);
        pd += __shfl_xor(pd, 1); pd += __shfl_xor(pd, 2); pd += __shfl_xor(pd, 4);
        if ((lane & 7) == 0) {
            als[n * 8 + (lane >> 3)] = ps;
            ald[n * 8 + (lane >> 3)] = pd;
        }
    }
}

// ---------------- gemm2 (VALU, small) ----------------
__global__ __launch_bounds__(256) void gemm2_kernel(
    const float* __restrict__ hin, const float* __restrict__ W,
    const float* __restrict__ a_src, const float* __restrict__ a_dst,
    __hip_bfloat16* __restrict__ h2, float* __restrict__ als,
    float* __restrict__ ald, int N) {
    __shared__ float rows[8 * 64];
    __shared__ float Ws[64 * 32];
    int t = threadIdx.x;
    int nb = blockIdx.x * 8;
    for (int i = t; i < 64 * 32; i += 256) Ws[i] = W[i];
    int nload = N - nb; if (nload > 8) nload = 8;
    for (int i = t; i < nload * 64; i += 256) rows[i] = hin[(size_t)nb * 64 + i];
    __syncthreads();
    int g = t >> 5, l = t & 31;
    int n = nb + g;
    if (n >= N) return;
    float acc = 0.f;
#pragma unroll 8
    for (int k = 0; k < 64; ++k) acc += rows[g * 64 + k] * Ws[k * 32 + l];
    h2[(size_t)n * 32 + l] = __float2bfloat16(acc);
    float ps = acc * a_src[l];
    float pd = acc * a_dst[l];
    ps += __shfl_xor(ps, 1); ps += __shfl_xor(ps, 2);
    pd += __shfl_xor(pd, 1); pd += __shfl_xor(pd, 2);
    if ((l & 3) == 0) {
        int hd = l >> 2;
        als[n * 8 + hd] = ps;
        ald[n * 8 + hd] = pd;
    }
}

// ---------------- fused GAT aggregation, F=64 ----------------
// One wave per node; 2 edges per iteration (lanes 0-31 edge a, 32-63 edge b);
// each lane covers channels 2l, 2l+1 via one bf16x2 load. Unroll x4 pairs.
__global__ __launch_bounds__(256) void gat_agg64_kernel(
    const int* __restrict__ rowp, const unsigned short* __restrict__ esrc,
    const __hip_bfloat16* __restrict__ feat, const float* __restrict__ als,
    const float* __restrict__ ald_arr, const float* __restrict__ bias,
    float* __restrict__ out, int N) {
    const int lane = threadIdx.x & 63;
    const int half = lane >> 5;          // edge slot within pair
    const int l = lane & 31;             // channel-pair index
    const int hd = l >> 2;               // head of channels 2l,2l+1 (C=8)
    int n = blockIdx.x * 4 + (threadIdx.x >> 6);
    if (n >= N) return;
    float aldv = ald_arr[n * 8 + hd];
    int beg = rowp[n], end = rowp[n + 1];
    float d0 = 0.f, d1 = 0.f, d2 = 0.f, d3 = 0.f;
    float p00 = 0.f, p01 = 0.f, p10 = 0.f, p11 = 0.f;
    float p20 = 0.f, p21 = 0.f, p30 = 0.f, p31 = 0.f;
    const unsigned int* fp = (const unsigned int*)feat;
    int i = beg;
    for (; i + 8 <= end; i += 8) {
        int s0 = esrc[i + half];
        int s1 = esrc[i + 2 + half];
        int s2 = esrc[i + 4 + half];
        int s3 = esrc[i + 6 + half];
        float e0 = als[s0 * 8 + hd] + aldv;
        float e1 = als[s1 * 8 + hd] + aldv;
        float e2 = als[s2 * 8 + hd] + aldv;
        float e3 = als[s3 * 8 + hd] + aldv;
        unsigned g0 = fp[s0 * 32 + l];
        unsigned g1 = fp[s1 * 32 + l];
        unsigned g2 = fp[s2 * 32 + l];
        unsigned g3 = fp[s3 * 32 + l];
        float w0 = __expf(lrelu(e0));
        float w1 = __expf(lrelu(e1));
        float w2 = __expf(lrelu(e2));
        float w3 = __expf(lrelu(e3));
        d0 += w0; p00 += w0 * bfl2f(g0); p01 += w0 * bfh2f(g0);
        d1 += w1; p10 += w1 * bfl2f(g1); p11 += w1 * bfh2f(g1);
        d2 += w2; p20 += w2 * bfl2f(g2); p21 += w2 * bfh2f(g2);
        d3 += w3; p30 += w3 * bfl2f(g3); p31 += w3 * bfh2f(g3);
    }
    for (; i + 2 <= end; i += 2) {
        int s = esrc[i + half];
        float e = als[s * 8 + hd] + aldv;
        unsigned g = fp[s * 32 + l];
        float w = __expf(lrelu(e));
        d0 += w; p00 += w * bfl2f(g); p01 += w * bfh2f(g);
    }
    if (i < end) {                        // odd final edge: slot 0 only
        int s = esrc[end - 1];
        float e = als[s * 8 + hd] + aldv;
        unsigned g = fp[s * 32 + l];
        float w = (half == 0) ? __expf(lrelu(e)) : 0.f;
        d0 += w; p00 += w * bfl2f(g); p01 += w * bfh2f(g);
    }
    float d = (d0 + d1) + (d2 + d3);
    float a0 = (p00 + p10) + (p20 + p30);
    float a1 = (p01 + p11) + (p21 + p31);
    d  += __shfl_xor(d, 32);
    a0 += __shfl_xor(a0, 32);
    a1 += __shfl_xor(a1, 32);
    if (half == 0) {
        float inv = 1.f / (d + 1e-16f);
        float2 bv = ((const float2*)bias)[l];
        float o0 = a0 * inv + bv.x;
        float o1 = a1 * inv + bv.y;
        o0 = (o0 > 0.f) ? o0 : (__expf(o0) - 1.f);
        o1 = (o1 > 0.f) ? o1 : (__expf(o1) - 1.f);
        ((float2*)(out + (size_t)n * 64))[l] = make_float2(o0, o1);
    }
}

// ---------------- fused GAT aggregation, F=32 ----------------
// 2 nodes/wave (half-wave each); within half: 2 edges x 16 lanes x 2 channels.
__global__ __launch_bounds__(256) void gat_agg32_kernel(
    const int* __restrict__ rowp, const unsigned short* __restrict__ esrc,
    const __hip_bfloat16* __restrict__ feat, const float* __restrict__ als,
    const float* __restrict__ ald_arr, const float* __restrict__ bias,
    float* __restrict__ out, int N) {
    const int lane = threadIdx.x & 63;
    const int nh = lane >> 5;            // node within wave
    const int l = lane & 31;
    const int sub = l >> 4;              // edge slot within pair
    const int j = l & 15;                // channel-pair -> ch 2j,2j+1
    const int hd = j >> 1;               // (2j)>>2, C=4
    int n = (blockIdx.x * 4 + (threadIdx.x >> 6)) * 2 + nh;
    bool valid = (n < N);
    int nn = valid ? n : 0;
    float aldv = ald_arr[nn * 8 + hd];
    int beg = rowp[nn];
    int end = valid ? rowp[nn + 1] : beg;
    float d0 = 0.f, d1 = 0.f, d2 = 0.f, d3 = 0.f;
    float p00 = 0.f, p01 = 0.f, p10 = 0.f, p11 = 0.f;
    float p20 = 0.f, p21 = 0.f, p30 = 0.f, p31 = 0.f;
    const unsigned int* fp = (const unsigned int*)feat;
    int i = beg;
    for (; i + 8 <= end; i += 8) {
        int s0 = esrc[i + sub];
        int s1 = esrc[i + 2 + sub];
        int s2 = esrc[i + 4 + sub];
        int s3 = esrc[i + 6 + sub];
        float e0 = als[s0 * 8 + hd] + aldv;
        float e1 = als[s1 * 8 + hd] + aldv;
        float e2 = als[s2 * 8 + hd] + aldv;
        float e3 = als[s3 * 8 + hd] + aldv;
        unsigned g0 = fp[s0 * 16 + j];
        unsigned g1 = fp[s1 * 16 + j];
        unsigned g2 = fp[s2 * 16 + j];
        unsigned g3 = fp[s3 * 16 + j];
        float w0 = __expf(lrelu(e0));
        float w1 = __expf(lrelu(e1));
        float w2 = __expf(lrelu(e2));
        float w3 = __expf(lrelu(e3));
        d0 += w0; p00 += w0 * bfl2f(g0); p01 += w0 * bfh2f(g0);
        d1 += w1; p10 += w1 * bfl2f(g1); p11 += w1 * bfh2f(g1);
        d2 += w2; p20 += w2 * bfl2f(g2); p21 += w2 * bfh2f(g2);
        d3 += w3; p30 += w3 * bfl2f(g3); p31 += w3 * bfh2f(g3);
    }
    for (; i + 2 <= end; i += 2) {
        int s = esrc[i + sub];
        float e = als[s * 8 + hd] + aldv;
        unsigned g = fp[s * 16 + j];
        float w = __expf(lrelu(e));
        d0 += w; p00 += w * bfl2f(g); p01 += w * bfh2f(g);
    }
    if (i < end) {
        int s = esrc[end - 1];
        float e = als[s * 8 + hd] + aldv;
        unsigned g = fp[s * 16 + j];
        float w = (sub == 0) ? __expf(lrelu(e)) : 0.f;
        d0 += w; p00 += w * bfl2f(g); p01 += w * bfh2f(g);
    }
    float d = (d0 + d1) + (d2 + d3);
    float a0 = (p00 + p10) + (p20 + p30);
    float a1 = (p01 + p11) + (p21 + p31);
    d  += __shfl_xor(d, 16);
    a0 += __shfl_xor(a0, 16);
    a1 += __shfl_xor(a1, 16);
    if (valid && sub == 0) {
        float inv = 1.f / (d + 1e-16f);
        float2 bv = ((const float2*)bias)[j];
        float o0 = a0 * inv + bv.x;
        float o1 = a1 * inv + bv.y;
        o0 = (o0 > 0.f) ? o0 : (__expf(o0) - 1.f);
        o1 = (o1 > 0.f) ? o1 : (__expf(o1) - 1.f);
        ((float2*)(out + (size_t)n * 32))[j] = make_float2(o0, o1);
    }
}

// ---------------- fold + final ----------------
__global__ __launch_bounds__(256) void fold_kernel(
    const float* __restrict__ in_proj_w, const float* __restrict__ in_proj_b,
    const float* __restrict__ out_proj_w, const float* __restrict__ out_proj_b,
    const float* __restrict__ fc_w, const float* __restrict__ fc_b,
    float* __restrict__ M, float* __restrict__ bf) {
    __shared__ float Wvo[32 * 32];
    __shared__ float bvo[32];
    const float* Wv = in_proj_w + 64 * 32;
    const float* bv = in_proj_b + 64;
    int t = threadIdx.x;
    for (int idx = t; idx < 1024; idx += 256) {
        int i = idx >> 5, j = idx & 31;
        float s = 0.f;
        for (int k = 0; k < 32; ++k) s += out_proj_w[i * 32 + k] * Wv[k * 32 + j];
        Wvo[idx] = s;
    }
    if (t < 32) {
        float s = 0.f;
        for (int k = 0; k < 32; ++k) s += out_proj_w[t * 32 + k] * bv[k];
        bvo[t] = s + out_proj_b[t];
    }
    __syncthreads();
    for (int idx = t; idx < 16 * 32; idx += 256) {
        int c = idx >> 5, j = idx & 31;
        float s = 0.f;
        for (int i = 0; i < 32; ++i) s += fc_w[c * 32 + i] * Wvo[i * 32 + j];
        M[idx] = s;
    }
    if (t < 16) {
        float s = 0.f;
        for (int i = 0; i < 32; ++i) s += fc_w[t * 32 + i] * bvo[i];
        bf[t] = s + fc_b[t];
    }
}

__global__ __launch_bounds__(256) void final_kernel(
    const float* __restrict__ h, const float* __restrict__ M,
    const float* __restrict__ bf, float* __restrict__ out, int N) {
    __shared__ float Ms[16 * 32];
    __shared__ float bfs[16];
    int t = threadIdx.x;
    for (int i = t; i < 512; i += 256) Ms[i] = M[i];
    if (t < 16) bfs[t] = bf[t];
    __syncthreads();
    int n = blockIdx.x * 256 + t;
    if (n >= N) return;
    float hv[32];
    const float4* hp = (const float4*)(h + (size_t)n * 32);
#pragma unroll
    for (int i = 0; i < 8; ++i) {
        float4 v = hp[i];
        hv[4 * i] = v.x; hv[4 * i + 1] = v.y; hv[4 * i + 2] = v.z; hv[4 * i + 3] = v.w;
    }
    float lg[16];
    float mx = -1e30f;
#pragma unroll
    for (int c = 0; c < 16; ++c) {
        float s = bfs[c];
#pragma unroll
        for (int j = 0; j < 32; ++j) s += Ms[c * 32 + j] * hv[j];
        lg[c] = s;
        mx = fmaxf(mx, s);
    }
    float se = 0.f;
#pragma unroll
    for (int c = 0; c < 16; ++c) se += __expf(lg[c] - mx);
    float lse = mx + __logf(se);
    float4* op = (float4*)(out + (size_t)n * 16);
#pragma unroll
    for (int i = 0; i < 4; ++i)
        op[i] = make_float4(lg[4 * i] - lse, lg[4 * i + 1] - lse,
                            lg[4 * i + 2] - lse, lg[4 * i + 3] - lse);
}

extern "C" void kernel_launch(void* const* d_in, const int* in_sizes, int n_in,
                              void* d_out, int out_size, void* d_ws, size_t ws_size,
                              hipStream_t stream) {
    const float* x   = (const float*)d_in[0];
    const int*   ei  = (const int*)d_in[1];
    const float* W1  = (const float*)d_in[2];
    const float* a1s = (const float*)d_in[3];
    const float* a1d = (const float*)d_in[4];
    const float* b1  = (const float*)d_in[5];
    const float* W2  = (const float*)d_in[6];
    const float* a2s = (const float*)d_in[7];
    const float* a2d = (const float*)d_in[8];
    const float* b2  = (const float*)d_in[9];
    const float* ipw = (const float*)d_in[10];
    const float* ipb = (const float*)d_in[11];
    const float* opw = (const float*)d_in[12];
    const float* opb = (const float*)d_in[13];
    const float* fcw = (const float*)d_in[14];
    const float* fcb = (const float*)d_in[15];
    float* out = (float*)d_out;

    int N = in_sizes[0] / 128;
    int E = in_sizes[1] / 2;
    int Et = E + N;
    int NB = (N + BMASK) >> BSHIFT;
    int NTILES = (Et + TILE - 1) / TILE;

    char* ws = (char*)d_ws;
    size_t off = 0;
    auto alloc = [&](size_t bytes) -> void* {
        void* p = ws + off;
        off += bytes;
        off = (off + 255) & ~(size_t)255;
        return p;
    };
    int*   bcount = (int*)alloc(MAXNB * 4);
    int*   bbase  = (int*)alloc(MAXNB * 4);
    int*   gcur   = (int*)alloc(MAXNB * 4);
    unsigned int*   rec  = (unsigned int*)alloc((size_t)Et * 4);
    int*   rowp   = (int*)alloc((size_t)(N + 1) * 4);
    unsigned short* esrc = (unsigned short*)alloc((size_t)Et * 2);
    __hip_bfloat16* h1 = (__hip_bfloat16*)alloc((size_t)N * 64 * 2);
    float* al1s  = (float*)alloc((size_t)N * 8 * 4);
    float* al1d  = (float*)alloc((size_t)N * 8 * 4);
    float* hout1 = (float*)alloc((size_t)N * 64 * 4);
    __hip_bfloat16* h2 = (__hip_bfloat16*)alloc((size_t)N * 32 * 2);
    float* al2s  = (float*)alloc((size_t)N * 8 * 4);
    float* al2d  = (float*)alloc((size_t)N * 8 * 4);
    float* out2  = (float*)alloc((size_t)N * 32 * 4);
    float* Mf    = (float*)alloc(512 * 4);
    float* bff   = (float*)alloc(16 * 4);
    (void)ws_size; (void)n_in; (void)out_size;

    hipMemsetAsync(bcount, 0, MAXNB * 4, stream);
    bin_count_kernel<<<NTILES, 256, 0, stream>>>(ei, E, Et, NB, bcount);
    bucket_scan_kernel<<<1, 512, 0, stream>>>(bcount, bbase, gcur, NB);
    bin_scatter_kernel<<<NTILES, 256, 0, stream>>>(ei, E, Et, NB, gcur, rec);
    csr_finalize_kernel<<<NB, 256, 0, stream>>>(rec, bcount, bbase, rowp, esrc, N, Et);

    gemm1_mfma_kernel<<<(N + 63) / 64, 256, 0, stream>>>(x, W1, a1s, a1d, h1, al1s, al1d, N);
    fold_kernel<<<1, 256, 0, stream>>>(ipw, ipb, opw, opb, fcw, fcb, Mf, bff);
    gat_agg64_kernel<<<(N + 3) / 4, 256, 0, stream>>>(
        rowp, esrc, h1, al1s, al1d, b1, hout1, N);
    gemm2_kernel<<<(N + 7) / 8, 256, 0, stream>>>(hout1, W2, a2s, a2d, h2, al2s, al2d, N);
    gat_agg32_kernel<<<(N + 7) / 8, 256, 0, stream>>>(
        rowp, esrc, h2, al2s, al2d, b2, out2, N);
    final_kernel<<<(N + 255) / 256, 256, 0, stream>>>(out2, Mf, bff, out, N);
}